// Round 13
// baseline (639.245 us; speedup 1.0000x reference)
//
#include <hip/hip_runtime.h>
#include <math.h>

typedef unsigned short ushort_t;
typedef __attribute__((ext_vector_type(8))) short short8;
typedef __attribute__((ext_vector_type(8))) unsigned short ushort8v;
typedef __attribute__((ext_vector_type(4))) float float4v;
typedef __attribute__((ext_vector_type(4))) unsigned short ushort4v;

#define MPAD 30016
#define H1STR 136

// ---------------- utility ----------------
__device__ __forceinline__ float lrelu02(float v){ return v > 0.f ? v : 0.2f*v; }
__device__ __forceinline__ float elu_fast(float v){ return v > 0.f ? v : (__expf(v) - 1.f); }

__device__ __forceinline__ ushort_t f2bf(float x){
  unsigned u = __float_as_uint(x);
  return (ushort_t)((u + 0x7fffu + ((u >> 16) & 1u)) >> 16);
}
__device__ __forceinline__ float bf2f(ushort_t h){ return __uint_as_float(((unsigned)h) << 16); }

// monotone float<->unsigned for atomicMax pooling
__device__ __forceinline__ unsigned encf(float f){
  unsigned u = __float_as_uint(f);
  return (u & 0x80000000u) ? ~u : (u | 0x80000000u);
}
__device__ __forceinline__ float decf(unsigned u){
  return __uint_as_float((u >> 31) ? (u & 0x7FFFFFFFu) : ~u);
}

__device__ __forceinline__ void gll16(const void* g, void* l){
  __builtin_amdgcn_global_load_lds((const __attribute__((address_space(1))) void*)g,
                                   (__attribute__((address_space(3))) void*)l, 16, 0, 0);
}

// ---------------- batched CSR build (both branches) ----------------
__global__ void hist2_k(const int* __restrict__ ei1, const int* __restrict__ ei2,
                        int E, int N, int* deg){
  int idx = blockIdx.x*blockDim.x + threadIdx.x;
  if (idx < 2*E){
    int br = idx / E, e = idx - br*E;
    const int* ei = br ? ei2 : ei1;
    atomicAdd(&deg[br*N + ei[E + e]], 1);
  }
}

__global__ __launch_bounds__(1024)
void scanA_k(const int* __restrict__ deg, int* __restrict__ rowptr, int* __restrict__ bsum, int n){
  int br = blockIdx.y;
  int t = threadIdx.x;
  int i = blockIdx.x*1024 + t;
  __shared__ int s[1024];
  int v = (i < n) ? (deg[br*n + i] + 1) : 0;   // +1 = self-loop
  s[t] = v; __syncthreads();
  for (int off = 1; off < 1024; off <<= 1){
    int x = (t >= off) ? s[t - off] : 0;
    __syncthreads();
    s[t] += x;
    __syncthreads();
  }
  if (i < n) rowptr[br*(n+1) + i] = s[t] - v;
  if (t == 1023) bsum[br*gridDim.x + blockIdx.x] = s[1023];
}

__global__ void scanB_k(int* bsum, int nb){
  int br = threadIdx.x;
  if (br < 2){
    int run = 0;
    for (int i = 0; i < nb; ++i){ int v = bsum[br*nb + i]; bsum[br*nb + i] = run; run += v; }
  }
}

__global__ __launch_bounds__(1024)
void scanC_k(const int* __restrict__ bsum, int* __restrict__ rowptr, int* __restrict__ cursor,
             int n, int nb, int total){
  int br = blockIdx.y;
  int i = blockIdx.x*1024 + threadIdx.x;
  int add = bsum[br*nb + blockIdx.x];
  if (i < n){
    int nv = rowptr[br*(n+1) + i] + add;
    rowptr[br*(n+1) + i] = nv;
    cursor[br*n + i] = nv;
  }
  if (i == 0) rowptr[br*(n+1) + n] = total;
}

// edges + self-loops in one pass (order within a row irrelevant)
__global__ void fill_csr2_k(const int* __restrict__ ei1, const int* __restrict__ ei2,
                            int E, int N, int* cursor, int* csr){
  int idx = blockIdx.x*blockDim.x + threadIdx.x;
  if (idx < 2*E){
    int br = idx / E, e = idx - br*E;
    const int* ei = br ? ei2 : ei1;
    int dst = ei[E + e];
    int pos = atomicAdd(&cursor[br*N + dst], 1);
    csr[br*(E+N) + pos] = ei[e];
  } else if (idx < 2*E + 2*N){
    int r = idx - 2*E;
    int br = r / N, i = r - br*N;
    int pos = atomicAdd(&cursor[br*N + i], 1);
    csr[br*(E+N) + pos] = i;
  }
}

// ---------------- attention score precompute (merged) ----------------
__global__ void mkattn_k(const float* __restrict__ W1, const float* __restrict__ a_src1,
                         const float* __restrict__ a_dst1,
                         const float* __restrict__ W2, const float* __restrict__ a_src2,
                         const float* __restrict__ a_dst2,
                         float* As, float* Ad, float* vs, float* vd){
  int idx = blockIdx.x*blockDim.x + threadIdx.x;
  if (idx < 780){
    int f = idx / 10, h = idx % 10;
    float ss = 0.f, sd = 0.f;
    for (int c = 0; c < 128; ++c){
      float w = W1[f*1280 + h*128 + c];
      ss += w * a_src1[h*128 + c];
      sd += w * a_dst1[h*128 + c];
    }
    As[idx] = ss; Ad[idx] = sd;
  } else if (idx < 2060){
    int k = idx - 780;
    float ss = 0.f, sd = 0.f;
    for (int c = 0; c < 128; ++c){
      float w = W2[k*128 + c];
      ss += w * a_src2[c]; sd += w * a_dst2[c];
    }
    vs[k] = ss; vd[k] = sd;
  }
}

// node-per-thread alpha1 (both branches); As/Ad staged in LDS
__global__ __launch_bounds__(256)
void alpha1b_k(const float* __restrict__ x1, const float* __restrict__ x2,
               const float* __restrict__ As, const float* __restrict__ Ad,
               float* as1, float* ad1, int n){
  __shared__ float sAs[780], sAd[780];
  int t = threadIdx.x;
  for (int k = t; k < 780; k += 256){ sAs[k] = As[k]; sAd[k] = Ad[k]; }
  __syncthreads();
  int idx = blockIdx.x*256 + t;
  if (idx >= 2*n) return;
  int br = idx / n, i = idx - br*n;
  const float* xr = (br ? x2 : x1) + (size_t)i*78;
  float ss[10], sd[10];
  #pragma unroll
  for (int h = 0; h < 10; ++h){ ss[h] = 0.f; sd[h] = 0.f; }
  for (int f = 0; f < 78; ++f){
    float xv = xr[f];
    #pragma unroll
    for (int h = 0; h < 10; ++h){
      ss[h] += xv * sAs[f*10 + h];
      sd[h] += xv * sAd[f*10 + h];
    }
  }
  #pragma unroll
  for (int h = 0; h < 10; ++h){
    as1[(size_t)idx*10 + h] = ss[h];
    ad1[(size_t)idx*10 + h] = sd[h];
  }
}

// ---------------- GATConv1 one-pass softmax + aggregate (both branches) ----------------
__global__ __launch_bounds__(64)
void gat1_agg_k(const int* __restrict__ rowptr2, const int* __restrict__ csr2,
                const float* __restrict__ x1, const float* __restrict__ x2,
                const float* __restrict__ as1b, const float* __restrict__ ad1b,
                ushort_t* __restrict__ yh, int n, int E){
  int gi = blockIdx.x;
  int br = (gi >= n) ? 1 : 0;
  int i = gi - br*n;
  int t = threadIdx.x;
  const int* rowptr = rowptr2 + (size_t)br*(n+1);
  const int* csr    = csr2 + (size_t)br*(E+n);
  const float* x    = br ? x2 : x1;
  const float* as1  = as1b + (size_t)br*n*10;
  ushort_t* yb      = yh + (size_t)br*10*MPAD*96;

  __shared__ float adi[10], rden[10], wE[10], xs[78];
  int beg = rowptr[i], end = rowptr[i+1];
  if (t < 10) adi[t] = ad1b[(size_t)gi*10 + t];
  __syncthreads();
  float den = 0.f;
  float acc[13];
  int hh[13], cc[13];
  #pragma unroll
  for (int k = 0; k < 13; ++k){
    acc[k] = 0.f;
    int j = t + 64*k;
    hh[k] = (j < 780) ? (j/78) : 0;
    cc[k] = (j < 780) ? (j%78) : 0;
  }
  for (int e = beg; e < end; ++e){
    int s = csr[e];
    if (t < 10){
      float w = __expf(lrelu02(as1[(size_t)s*10 + t] + adi[t]));
      wE[t] = w; den += w;
    }
    for (int c = t; c < 78; c += 64) xs[c] = x[(size_t)s*78 + c];
    __syncthreads();
    #pragma unroll
    for (int k = 0; k < 13; ++k){
      int j = t + 64*k;
      if (j < 780) acc[k] += wE[hh[k]] * xs[cc[k]];
    }
    __syncthreads();
  }
  if (t < 10) rden[t] = 1.f/(den + 1e-16f);
  __syncthreads();
  #pragma unroll
  for (int k = 0; k < 13; ++k){
    int j = t + 64*k;
    if (j < 780) yb[((size_t)hh[k]*MPAD + i)*96 + cc[k]] = f2bf(acc[k]*rden[hh[k]]);
  }
  for (int p = t; p < 180; p += 64){
    int h = p/18, c = 78 + p%18;
    yb[((size_t)h*MPAD + i)*96 + c] = 0;
  }
}

// ---------------- fused branch conv (direct-load GEMMs; LDS only for h1t) ----------------
// A/B fragments loaded global->VGPR (W1h/W2h are L2-resident; y streamed, 2x read hits L2).
// Only 2 barriers per head (h1t transpose WAR/RAW). 18.4 KB LDS.
__global__ __launch_bounds__(256, 4)
void branch_conv_k(const ushort_t* __restrict__ yall,
                   const ushort_t* __restrict__ W1h, const ushort_t* __restrict__ W2h,
                   const float* __restrict__ b1, const float* __restrict__ vs,
                   const float* __restrict__ vd,
                   ushort_t* __restrict__ h2all, float* __restrict__ as2all,
                   float* __restrict__ ad2all, int M){
  const int NBLK = MPAD/64;
  int br = blockIdx.x / NBLK;
  int bi = blockIdx.x - br*NBLK;
  const ushort_t* y = yall + (size_t)br*10*MPAD*96;
  ushort_t* h2 = h2all + (size_t)br*MPAD*128;
  float* as2 = as2all + (size_t)br*MPAD;
  float* ad2 = ad2all + (size_t)br*MPAD;

  __shared__ __align__(16) ushort_t h1t[64*H1STR];   // 17408 B
  __shared__ float red[256];

  int tid = threadIdx.x, lane = tid & 63, wave = tid >> 6;
  int row0 = bi*64;
  int wm = (wave & 1)*32, wn = (wave >> 1)*64;
  int lr = lane & 15, quad = lane >> 4;

  float4v acc2[2][4];
  #pragma unroll
  for (int i = 0; i < 2; ++i)
    #pragma unroll
    for (int j = 0; j < 4; ++j)
      acc2[i][j] = (float4v){0.f, 0.f, 0.f, 0.f};
  float rps[8], rpd[8];
  #pragma unroll
  for (int z = 0; z < 8; ++z){ rps[z] = 0.f; rpd[z] = 0.f; }

  for (int h = 0; h < 10; ++h){
    // ---- P1: h1e_h = y_h @ W1_h (K=96), fragments direct from global ----
    float4v acc1[2][4];
    #pragma unroll
    for (int i = 0; i < 2; ++i)
      #pragma unroll
      for (int j = 0; j < 4; ++j)
        acc1[i][j] = (float4v){0.f, 0.f, 0.f, 0.f};
    #pragma unroll
    for (int it = 0; it < 3; ++it){
      short8 af[2], bf[4];
      #pragma unroll
      for (int t2 = 0; t2 < 2; ++t2)
        af[t2] = *(const short8*)&y[((size_t)h*MPAD + row0 + wm + t2*16 + lr)*96 + it*32 + quad*8];
      #pragma unroll
      for (int j = 0; j < 4; ++j)
        bf[j] = *(const short8*)&W1h[((size_t)(h*128 + wn + j*16 + lr))*96 + it*32 + quad*8];
      #pragma unroll
      for (int i = 0; i < 2; ++i)
        #pragma unroll
        for (int j = 0; j < 4; ++j)
          acc1[i][j] = __builtin_amdgcn_mfma_f32_16x16x32_bf16(af[i], bf[j], acc1[i][j], 0, 0, 0);
    }

    // ---- ELU + bias; write h1t; accumulate alpha2 from fp32 values ----
    #pragma unroll
    for (int j = 0; j < 4; ++j){
      int col = wn + j*16 + lr;
      float bv  = b1[h*128 + col];
      float vsv = vs[h*128 + col];
      float vdv = vd[h*128 + col];
      #pragma unroll
      for (int i = 0; i < 2; ++i){
        #pragma unroll
        for (int r = 0; r < 4; ++r){
          float v = elu_fast(acc1[i][j][r] + bv);
          h1t[(wm + i*16 + quad*4 + r)*H1STR + col] = f2bf(v);
          rps[i*4 + r] += v * vsv;
          rpd[i*4 + r] += v * vdv;
        }
      }
    }
    __syncthreads();   // h1t visible to all waves

    // ---- P2: h2 += h1t @ W2[h*128:(h+1)*128, :] (K=128); B direct from global ----
    #pragma unroll
    for (int it = 0; it < 4; ++it){
      int kt = it*32;
      short8 af[2], bf[4];
      #pragma unroll
      for (int t2 = 0; t2 < 2; ++t2)
        af[t2] = *(const short8*)&h1t[(wm + t2*16 + lr)*H1STR + kt + quad*8];
      #pragma unroll
      for (int j = 0; j < 4; ++j)
        bf[j] = *(const short8*)&W2h[((size_t)(wn + j*16 + lr))*1280 + h*128 + kt + quad*8];
      #pragma unroll
      for (int i = 0; i < 2; ++i)
        #pragma unroll
        for (int j = 0; j < 4; ++j)
          acc2[i][j] = __builtin_amdgcn_mfma_f32_16x16x32_bf16(af[i], bf[j], acc2[i][j], 0, 0, 0);
    }
    __syncthreads();   // h1t reads done before next head overwrites
  }

  // ---- h2 store (bf16) ----
  #pragma unroll
  for (int j = 0; j < 4; ++j){
    int col = wn + j*16 + lr;
    #pragma unroll
    for (int i = 0; i < 2; ++i){
      #pragma unroll
      for (int r = 0; r < 4; ++r){
        int row = row0 + wm + i*16 + quad*4 + r;
        if (row < M) h2[(size_t)row*128 + col] = f2bf(acc2[i][j][r]);
      }
    }
  }
  // ---- alpha2 reduce ----
  __syncthreads();
  #pragma unroll
  for (int z = 0; z < 8; ++z){
    float a = rps[z], d = rpd[z];
    #pragma unroll
    for (int mk = 1; mk <= 8; mk <<= 1){
      a += __shfl_xor(a, mk);
      d += __shfl_xor(d, mk);
    }
    if (lr == 0){
      int i = z >> 2, r = z & 3;
      int row = wm + i*16 + quad*4 + r;
      red[row*2 + (wave >> 1)] = a;
      red[128 + row*2 + (wave >> 1)] = d;
    }
  }
  __syncthreads();
  if (tid < 64){
    int grow = row0 + tid;
    if (grow < M){
      as2[grow] = red[tid*2] + red[tid*2 + 1];
      ad2[grow] = red[128 + tid*2] + red[128 + tid*2 + 1];
    }
  }
}

// ---------------- GATConv2 one-pass softmax + aggregate + atomic pool (bf16 h2) ----------------
__global__ __launch_bounds__(64)
void gat2_agg_k(const int* __restrict__ rowptr2, const int* __restrict__ csr2,
                const ushort_t* __restrict__ h2all, const float* __restrict__ as2all,
                const float* __restrict__ ad2all, const float* __restrict__ b2,
                const int* __restrict__ batch1, const int* __restrict__ batch2,
                unsigned* __restrict__ poolKey, int n, int E, int Bg){
  int gi = blockIdx.x;
  int br = (gi >= n) ? 1 : 0;
  int i = gi - br*n;
  int t = threadIdx.x;
  const int* rowptr = rowptr2 + (size_t)br*(n+1);
  const int* csr    = csr2 + (size_t)br*(E+n);
  const ushort_t* h2 = h2all + (size_t)br*MPAD*128;
  const float* as2  = as2all + (size_t)br*MPAD;
  float adi = ad2all[(size_t)br*MPAD + i];
  int beg = rowptr[i], end = rowptr[i+1];
  float den = 0.f, a0 = 0.f, a1 = 0.f;
  for (int e = beg; e < end; ++e){
    int s = csr[e];
    float w = __expf(lrelu02(as2[s] + adi));
    den += w;
    unsigned u = *(const unsigned*)&h2[(size_t)s*128 + 2*t];
    a0 += w * bf2f((ushort_t)(u & 0xffffu));
    a1 += w * bf2f((ushort_t)(u >> 16));
  }
  float r = 1.f/(den + 1e-16f);
  float o0 = elu_fast(a0*r + b2[2*t]);
  float o1 = elu_fast(a1*r + b2[2*t + 1]);
  int g = (br ? batch2 : batch1)[i];
  unsigned* pk = poolKey + ((size_t)br*Bg + g)*128;
  atomicMax(&pk[2*t], encf(o0));
  atomicMax(&pk[2*t + 1], encf(o1));
}

// ---------------- pool decode → split bf16 ----------------
__global__ void pool_decode_k(const unsigned* __restrict__ key,
                              ushort_t* __restrict__ ph, ushort_t* __restrict__ pl, int n){
  int i = blockIdx.x*blockDim.x + threadIdx.x;
  if (i < n){
    float v = decf(key[i]);
    ushort_t h = f2bf(v);
    ph[i] = h; pl[i] = f2bf(v - bf2f(h));
  }
}

// ---------------- row-wise L2 normalize → split bf16 (K-padded) ----------------
__global__ __launch_bounds__(256)
void l2norm_split_k(const float* __restrict__ in, int cols, int Kp,
                    ushort_t* __restrict__ oh, ushort_t* __restrict__ ol){
  int r = blockIdx.x, t = threadIdx.x;
  __shared__ float s[256];
  __shared__ float scaleS;
  const float* rp = in + (size_t)r*cols;
  float p = 0.f;
  for (int k = t; k < cols; k += 256){ float v = rp[k]; p += v*v; }
  s[t] = p; __syncthreads();
  for (int o = 128; o > 0; o >>= 1){
    if (t < o) s[t] += s[t+o];
    __syncthreads();
  }
  if (t == 0) scaleS = 1.f / fmaxf(sqrtf(s[0]), 1e-12f);
  __syncthreads();
  float sc = scaleS;
  for (int k = t; k < Kp; k += 256){
    float v = (k < cols) ? rp[k]*sc : 0.f;
    ushort_t h = f2bf(v);
    size_t o2 = (size_t)r*Kp + k;
    oh[o2] = h; ol[o2] = f2bf(v - bf2f(h));
  }
}

// ---------------- fused concat + l2norm + split ----------------
__global__ __launch_bounds__(256)
void catnorm_k(const float* __restrict__ vall, const float* __restrict__ c3,
               ushort_t* __restrict__ oh, ushort_t* __restrict__ ol, int Bg){
  int r = blockIdx.x, t = threadIdx.x;
  __shared__ float s[256];
  __shared__ float scaleS;
  auto val = [&](int c)->float{
    if (c < 128) return vall[(size_t)r*128 + c];
    if (c < 256) return vall[((size_t)Bg + r)*128 + (c - 128)];
    return c3[(size_t)r*256 + (c - 256)];
  };
  float v0 = val(t), v1 = val(t + 256);
  s[t] = v0*v0 + v1*v1; __syncthreads();
  for (int o = 128; o > 0; o >>= 1){
    if (t < o) s[t] += s[t+o];
    __syncthreads();
  }
  if (t == 0) scaleS = 1.f / fmaxf(sqrtf(s[0]), 1e-12f);
  __syncthreads();
  float sc = scaleS;
  float a = v0*sc, b = v1*sc;
  ushort_t ha = f2bf(a), hb = f2bf(b);
  size_t o2 = (size_t)r*512;
  oh[o2 + t] = ha;       ol[o2 + t] = f2bf(a - bf2f(ha));
  oh[o2 + 256 + t] = hb; ol[o2 + 256 + t] = f2bf(b - bf2f(hb));
}

// relu + split (post split-K reduction)
__global__ void act_split_k(const float* __restrict__ in, ushort_t* __restrict__ oh,
                            ushort_t* __restrict__ ol, int n){
  int i = blockIdx.x*blockDim.x + threadIdx.x;
  if (i < n){
    float v = fmaxf(in[i], 0.f);
    ushort_t h = f2bf(v);
    oh[i] = h; ol[i] = f2bf(v - bf2f(h));
  }
}

// ---------------- merged weight transpose + split ----------------
__device__ __forceinline__ void split_one(const float* __restrict__ W, int ldw, int colStride,
                                          int N, int K, int Np, int Kp,
                                          ushort_t* __restrict__ dh, ushort_t* __restrict__ dl,
                                          int idx){
  int n  = idx % Np;
  int r  = idx / Np;
  int k4 = r % (Kp >> 2);
  int b  = r / (Kp >> 2);
  size_t o = ((size_t)b*Np + n)*Kp + (size_t)k4*4;
  ushort4v hv, lv;
  #pragma unroll
  for (int kk = 0; kk < 4; ++kk){
    int k = k4*4 + kk;
    float v = (n < N && k < K) ? W[(size_t)k*ldw + (size_t)b*colStride + n] : 0.f;
    ushort_t h = f2bf(v);
    hv[kk] = h; lv[kk] = f2bf(v - bf2f(h));
  }
  *(ushort4v*)&dh[o] = hv;
  if (dl) *(ushort4v*)&dl[o] = lv;
}

struct SplitTable {
  const float *W1, *W2, *Wg, *Wr1, *Wr2, *Wr3, *Wf1, *Wf2, *Wf3, *Wo;
  ushort_t *W1h,*W2h,*Wgh,*Wgl,*Wr1h,*Wr1l,*Wr2h,*Wr2l;
  ushort_t *Wr3h,*Wr3l,*Wf1h,*Wf1l,*Wf2h,*Wf2l,*Wf3h,*Wf3l,*Woh,*Wol;
};

__global__ void split_all_k(SplitTable T){
  int idx = blockIdx.x*blockDim.x + threadIdx.x;
  if      (idx <   30720) split_one(T.W1, 1280, 128, 128,   78,  128,   96, T.W1h, nullptr, idx);
  else if (idx <   71680) split_one(T.W2,  128,   0, 128, 1280,  128, 1280, T.W2h, nullptr, idx -   30720);
  else if (idx <   75776) split_one(T.Wg,  128,   0, 128,  128,  128,  128, T.Wgh, T.Wgl, idx -   71680);
  else if (idx <  567296) split_one(T.Wr1,2048,   0,2048,  954, 2048,  960, T.Wr1h,T.Wr1l,idx -   75776);
  else if (idx <  829440) split_one(T.Wr2, 512,   0, 512, 2048,  512, 2048, T.Wr2h,T.Wr2l,idx -  567296);
  else if (idx <  862208) split_one(T.Wr3, 256,   0, 256,  512,  256,  512, T.Wr3h,T.Wr3l,idx -  829440);
  else if (idx <  993280) split_one(T.Wf1,1024,   0,1024,  512, 1024,  512, T.Wf1h,T.Wf1l,idx -  862208);
  else if (idx < 1124352) split_one(T.Wf2, 512,   0, 512, 1024,  512, 1024, T.Wf2h,T.Wf2l,idx -  993280);
  else if (idx < 1140736) split_one(T.Wf3, 128,   0, 128,  512,  128,  512, T.Wf3h,T.Wf3l,idx - 1124352);
  else if (idx < 1142784) split_one(T.Wo,    2,   0,   2,  128,   64,  128, T.Woh, T.Wol, idx - 1140736);
}

// ---------------- split-bf16 MFMA GEMM (MLP path) ----------------
__global__ __launch_bounds__(256)
void gemm_split(const ushort_t* __restrict__ Ahp, const ushort_t* __restrict__ Alp, int lda, long long sA,
                const ushort_t* __restrict__ Bhp, const ushort_t* __restrict__ Blp, int ldb, long long sB,
                float* __restrict__ C, ushort_t* __restrict__ Ch, ushort_t* __restrict__ Cl,
                int ldc, long long sC,
                const float* __restrict__ bias, int sBias,
                int M, int Nc, int K, int act, int outMode, int kSplit, int aSplit){
  int zb = blockIdx.z;
  int b = zb / kSplit, kc = zb - b*kSplit;
  Ahp += (long long)b*sA;
  Bhp += (long long)b*sB; Blp += (long long)b*sB;
  long long cOff = (long long)b*sC;
  int Kc = K / kSplit;
  int kb = kc*Kc;
  int nIter = Kc / 32;

  __shared__ ushort_t smem[18048];

  int tid = threadIdx.x, lane = tid & 63, wave = tid >> 6;
  int row0 = blockIdx.y*64, col0 = blockIdx.x*64;
  int wm = (wave & 1)*32, wn = (wave >> 1)*32;
  int lr = lane & 15, quad = lane >> 4;
  int qs = (quad ^ ((lr >> 1) & 3)) * 8;

  int srow = wave*16 + (lane >> 2);
  int skc  = (((lane & 3) ^ ((lane >> 3) & 3)) * 8);
  const ushort_t* gAh = Ahp + (long long)(row0 + srow)*lda + skc + kb;
  const ushort_t* gAl = aSplit ? (Alp + (long long)b*sA + (long long)(row0 + srow)*lda + skc + kb) : gAh;
  const ushort_t* gBh = Bhp + (long long)(col0 + srow)*ldb + skc + kb;
  const ushort_t* gBl = Blp + (long long)(col0 + srow)*ldb + skc + kb;

  float4v acc[2][2];
  #pragma unroll
  for (int i = 0; i < 2; ++i)
    #pragma unroll
    for (int j = 0; j < 2; ++j)
      acc[i][j] = (float4v){0.f, 0.f, 0.f, 0.f};

  auto issue = [&](int p, int kt){
    ushort_t* base = &smem[p*8192 + wave*512];
    gll16(gAh + kt, base);
    if (aSplit) gll16(gAl + kt, base + 2048);
    gll16(gBh + kt, base + 4096);
    gll16(gBl + kt, base + 6144);
  };

  issue(0, 0);
  int p = 0;
  for (int it = 0; it < nIter; ++it){
    __syncthreads();
    if (it + 1 < nIter) issue(p ^ 1, (it + 1)*32);
    const ushort_t* sm = &smem[p*8192];
    short8 ah[2], al[2], bh[2], bl[2];
    #pragma unroll
    for (int t2 = 0; t2 < 2; ++t2){
      int ao = (wm + t2*16 + lr)*32 + qs;
      int bo = (wn + t2*16 + lr)*32 + qs;
      ah[t2] = *(const short8*)&sm[ao];
      if (aSplit) al[t2] = *(const short8*)&sm[2048 + ao];
      bh[t2] = *(const short8*)&sm[4096 + bo];
      bl[t2] = *(const short8*)&sm[6144 + bo];
    }
    #pragma unroll
    for (int i = 0; i < 2; ++i)
      #pragma unroll
      for (int j = 0; j < 2; ++j){
        if (aSplit)
          acc[i][j] = __builtin_amdgcn_mfma_f32_16x16x32_bf16(al[i], bh[j], acc[i][j], 0, 0, 0);
        acc[i][j] = __builtin_amdgcn_mfma_f32_16x16x32_bf16(ah[i], bl[j], acc[i][j], 0, 0, 0);
        acc[i][j] = __builtin_amdgcn_mfma_f32_16x16x32_bf16(ah[i], bh[j], acc[i][j], 0, 0, 0);
      }
    p ^= 1;
  }
  __syncthreads();

  if (outMode == 0 || outMode == 2){
    #pragma unroll
    for (int j = 0; j < 2; ++j){
      int col = col0 + wn + j*16 + lr;
      if (col >= Nc) continue;
      float bv = (bias && kc == 0) ? bias[(long long)b*sBias + col] : 0.f;
      #pragma unroll
      for (int i = 0; i < 2; ++i){
        #pragma unroll
        for (int r = 0; r < 4; ++r){
          int row = row0 + wm + i*16 + quad*4 + r;
          if (row >= M) continue;
          float v = acc[i][j][r] + bv;
          if (act == 1) v = fmaxf(v, 0.f);
          else if (act == 2) v = elu_fast(v);
          long long o = cOff + (long long)row*ldc + col;
          if (outMode == 0) C[o] = v;
          else atomicAdd(&C[o], v);
        }
      }
    }
  } else {
    float* ftile = (float*)smem;
    #pragma unroll
    for (int i = 0; i < 2; ++i)
      #pragma unroll
      for (int j = 0; j < 2; ++j)
        #pragma unroll
        for (int r = 0; r < 4; ++r)
          ftile[(wm + i*16 + quad*4 + r)*68 + wn + j*16 + lr] = acc[i][j][r];
    __syncthreads();
    int row = tid >> 2, ch = (tid & 3)*16;
    int grow = row0 + row;
    if (grow < M){
      if (col0 + 64 <= Nc){
        long long o = cOff + (long long)grow*ldc + col0 + ch;
        #pragma unroll
        for (int g = 0; g < 2; ++g){
          ushort8v hv, lv;
          #pragma unroll
          for (int c = 0; c < 8; ++c){
            int cc2 = ch + g*8 + c;
            float v = ftile[row*68 + cc2];
            if (bias) v += bias[(long long)b*sBias + col0 + cc2];
            if (act == 1) v = fmaxf(v, 0.f);
            else if (act == 2) v = elu_fast(v);
            hv[c] = f2bf(v);
            lv[c] = f2bf(v - bf2f(hv[c]));
          }
          *(ushort8v*)&Ch[o + g*8] = hv;
          *(ushort8v*)&Cl[o + g*8] = lv;
        }
      } else {
        for (int c = 0; c < 16; ++c){
          int col = col0 + ch + c;
          if (col >= Nc) break;
          float v = ftile[row*68 + ch + c];
          if (bias) v += bias[(long long)b*sBias + col];
          if (act == 1) v = fmaxf(v, 0.f);
          else if (act == 2) v = elu_fast(v);
          long long o = cOff + (long long)grow*ldc + col;
          ushort_t h = f2bf(v);
          Ch[o] = h;
          Cl[o] = f2bf(v - bf2f(h));
        }
      }
    }
  }
}

// ---------------- host launch ----------------
extern "C" void kernel_launch(void* const* d_in, const int* in_sizes, int n_in,
                              void* d_out, int out_size, void* d_ws, size_t ws_size,
                              hipStream_t stream){
  const float* x1     = (const float*)d_in[0];
  const int*   ei1    = (const int*)  d_in[1];
  const int*   batch1 = (const int*)  d_in[2];
  const float* x2     = (const float*)d_in[3];
  const int*   ei2    = (const int*)  d_in[4];
  const int*   batch2 = (const int*)  d_in[5];
  const float* cell   = (const float*)d_in[6];
  const float* W1     = (const float*)d_in[7];
  const float* a_src1 = (const float*)d_in[8];
  const float* a_dst1 = (const float*)d_in[9];
  const float* b1     = (const float*)d_in[10];
  const float* W2     = (const float*)d_in[11];
  const float* a_src2 = (const float*)d_in[12];
  const float* a_dst2 = (const float*)d_in[13];
  const float* b2     = (const float*)d_in[14];
  const float* Wg     = (const float*)d_in[15];
  const float* bg     = (const float*)d_in[16];
  const float* Wr1    = (const float*)d_in[17];
  const float* br1    = (const float*)d_in[18];
  const float* Wr2    = (const float*)d_in[19];
  const float* br2    = (const float*)d_in[20];
  const float* Wr3    = (const float*)d_in[21];
  const float* br3    = (const float*)d_in[22];
  const float* Wf1    = (const float*)d_in[23];
  const float* bf1    = (const float*)d_in[24];
  const float* Wf2    = (const float*)d_in[25];
  const float* bf2    = (const float*)d_in[26];
  const float* Wf3    = (const float*)d_in[27];
  const float* bf3    = (const float*)d_in[28];
  const float* Wo     = (const float*)d_in[29];
  const float* bo     = (const float*)d_in[30];
  float* out = (float*)d_out;
  (void)n_in; (void)out_size; (void)ws_size;

  const int N  = in_sizes[0] / 78;
  const int E  = in_sizes[1] / 2;
  const int Bg = in_sizes[6] / 954;

  char* wsb = (char*)d_ws;
  size_t off = 0;
  auto alloc = [&](size_t bytes)->char*{
    char* p = wsb + off; off += ((bytes + 255)/256)*256; return p;
  };

  // Y region: yh (both branches) during branch phase; MLP bufs alias after
  char* Yb = alloc((size_t)2*10*MPAD*96*2);
  ushort_t* yh = (ushort_t*)Yb;
  size_t yoff = 0;
  auto yalloc = [&](size_t bytes)->char*{
    char* p = Yb + yoff; yoff += ((bytes + 255)/256)*256; return p;
  };
  ushort_t* cnh  = (ushort_t*)yalloc((size_t)Bg*960*2);
  ushort_t* cnl  = (ushort_t*)yalloc((size_t)Bg*960*2);
  ushort_t* c1h  = (ushort_t*)yalloc((size_t)Bg*2048*2);
  ushort_t* c1l  = (ushort_t*)yalloc((size_t)Bg*2048*2);
  ushort_t* c2h  = (ushort_t*)yalloc((size_t)Bg*512*2);
  ushort_t* c2l  = (ushort_t*)yalloc((size_t)Bg*512*2);
  float*    c3   = (float*)   yalloc((size_t)Bg*256*4);
  ushort_t* xcnh = (ushort_t*)yalloc((size_t)Bg*512*2);
  ushort_t* xcnl = (ushort_t*)yalloc((size_t)Bg*512*2);
  ushort_t* t1h  = (ushort_t*)yalloc((size_t)Bg*1024*2);
  ushort_t* t1l  = (ushort_t*)yalloc((size_t)Bg*1024*2);
  ushort_t* t2h  = (ushort_t*)yalloc((size_t)Bg*512*2);
  ushort_t* t2l  = (ushort_t*)yalloc((size_t)Bg*512*2);
  ushort_t* t3h  = (ushort_t*)yalloc((size_t)Bg*128*2);
  ushort_t* t3l  = (ushort_t*)yalloc((size_t)Bg*128*2);
  ushort_t* pooledh = (ushort_t*)yalloc((size_t)2*Bg*128*2);
  ushort_t* pooledl = (ushort_t*)yalloc((size_t)2*Bg*128*2);
  float*    vall    = (float*)   yalloc((size_t)2*Bg*128*4);

  // zero-init region (single memset): c2f, poolKey, deg2
  size_t zElems = (size_t)Bg*512 + (size_t)2*Bg*128 + (size_t)2*N;
  float* zbase = (float*)alloc(zElems*4);
  float* c2f = zbase;
  unsigned* poolKey = (unsigned*)(c2f + (size_t)Bg*512);
  int* deg2 = (int*)(poolKey + (size_t)2*Bg*128);

  ushort_t* h2 = (ushort_t*)alloc((size_t)2*MPAD*128*2);
  float* as2 = (float*)alloc((size_t)2*MPAD*4);
  float* ad2 = (float*)alloc((size_t)2*MPAD*4);

  // transposed weights: W1/W2 hi-only; MLP weights split
  ushort_t* W1th = (ushort_t*)alloc((size_t)10*128*96*2);
  ushort_t* W2th = (ushort_t*)alloc((size_t)128*1280*2);
  ushort_t* Wgth = (ushort_t*)alloc((size_t)128*128*2);
  ushort_t* Wgtl = (ushort_t*)alloc((size_t)128*128*2);
  ushort_t* Wr1th= (ushort_t*)alloc((size_t)2048*960*2);
  ushort_t* Wr1tl= (ushort_t*)alloc((size_t)2048*960*2);
  ushort_t* Wr2th= (ushort_t*)alloc((size_t)512*2048*2);
  ushort_t* Wr2tl= (ushort_t*)alloc((size_t)512*2048*2);
  ushort_t* Wr3th= (ushort_t*)alloc((size_t)256*512*2);
  ushort_t* Wr3tl= (ushort_t*)alloc((size_t)256*512*2);
  ushort_t* Wf1th= (ushort_t*)alloc((size_t)1024*512*2);
  ushort_t* Wf1tl= (ushort_t*)alloc((size_t)1024*512*2);
  ushort_t* Wf2th= (ushort_t*)alloc((size_t)512*1024*2);
  ushort_t* Wf2tl= (ushort_t*)alloc((size_t)512*1024*2);
  ushort_t* Wf3th= (ushort_t*)alloc((size_t)128*512*2);
  ushort_t* Wf3tl= (ushort_t*)alloc((size_t)128*512*2);
  ushort_t* Woth = (ushort_t*)alloc((size_t)64*128*2);
  ushort_t* Wotl = (ushort_t*)alloc((size_t)64*128*2);

  float* as1b = (float*)alloc((size_t)2*N*10*4);
  float* ad1b = (float*)alloc((size_t)2*N*10*4);
  float* AsB  = (float*)alloc(780*4);
  float* AdB  = (float*)alloc(780*4);
  float* vs   = (float*)alloc(1280*4);
  float* vd   = (float*)alloc(1280*4);
  int* rowptr2 = (int*)alloc((size_t)2*(N+1)*4);
  int* cursor2 = (int*)alloc((size_t)2*N*4);
  int* csr2    = (int*)alloc((size_t)2*(E+N)*4);
  int* bsum    = (int*)alloc((size_t)2*64*4);

  auto gemm = [&](const ushort_t* Ah_, const ushort_t* Al_, int lda, long long sA_,
                  const ushort_t* Bh_, const ushort_t* Bl_, int ldb, long long sB_,
                  float* C_, ushort_t* Ch_, ushort_t* Cl_, int ldc, long long sC_,
                  const float* bias_, int sBias_, int M_, int N_, int K_, int batch_,
                  int act_, int mode_, int kSplit_, int aSplit_){
    dim3 grid((N_ + 63)/64, (M_ + 63)/64, batch_*kSplit_);
    gemm_split<<<grid, 256, 0, stream>>>(Ah_, Al_, lda, sA_, Bh_, Bl_, ldb, sB_,
                                         C_, Ch_, Cl_, ldc, sC_, bias_, sBias_,
                                         M_, N_, K_, act_, mode_, kSplit_, aSplit_);
  };

  // ---- init + weight prep ----
  hipMemsetAsync(zbase, 0, zElems*4, stream);
  SplitTable T;
  T.W1 = W1; T.W2 = W2; T.Wg = Wg; T.Wr1 = Wr1; T.Wr2 = Wr2; T.Wr3 = Wr3;
  T.Wf1 = Wf1; T.Wf2 = Wf2; T.Wf3 = Wf3; T.Wo = Wo;
  T.W1h = W1th; T.W2h = W2th; T.Wgh = Wgth; T.Wgl = Wgtl;
  T.Wr1h = Wr1th; T.Wr1l = Wr1tl; T.Wr2h = Wr2th; T.Wr2l = Wr2tl;
  T.Wr3h = Wr3th; T.Wr3l = Wr3tl; T.Wf1h = Wf1th; T.Wf1l = Wf1tl;
  T.Wf2h = Wf2th; T.Wf2l = Wf2tl; T.Wf3h = Wf3th; T.Wf3l = Wf3tl;
  T.Woh = Woth; T.Wol = Wotl;
  split_all_k<<<(1142784 + 255)/256, 256, 0, stream>>>(T);
  mkattn_k<<<(2060 + 255)/256, 256, 0, stream>>>(W1, a_src1, a_dst1, W2, a_src2, a_dst2,
                                                 AsB, AdB, vs, vd);
  alpha1b_k<<<((2*N) + 255)/256, 256, 0, stream>>>(x1, x2, AsB, AdB, as1b, ad1b, N);

  // ---- batched CSR build ----
  const int NB = (N + 1023)/1024;
  hist2_k<<<((2*E) + 255)/256, 256, 0, stream>>>(ei1, ei2, E, N, deg2);
  scanA_k<<<dim3(NB, 2), 1024, 0, stream>>>(deg2, rowptr2, bsum, N);
  scanB_k<<<1, 64, 0, stream>>>(bsum, NB);
  scanC_k<<<dim3(NB, 2), 1024, 0, stream>>>(bsum, rowptr2, cursor2, N, NB, E + N);
  fill_csr2_k<<<((2*E + 2*N) + 255)/256, 256, 0, stream>>>(ei1, ei2, E, N, cursor2, csr2);

  // ---- branches (batched) ----
  gat1_agg_k<<<2*N, 64, 0, stream>>>(rowptr2, csr2, x1, x2, as1b, ad1b, yh, N, E);
  branch_conv_k<<<2*(MPAD/64), 256, 0, stream>>>(yh, W1th, W2th,
                                                 b1, vs, vd, h2, as2, ad2, N);
  gat2_agg_k<<<2*N, 64, 0, stream>>>(rowptr2, csr2, h2, as2, ad2, b2,
                                     batch1, batch2, poolKey, N, E, Bg);
  pool_decode_k<<<((2*Bg*128) + 255)/256, 256, 0, stream>>>(poolKey, pooledh, pooledl, 2*Bg*128);
  gemm(pooledh, pooledl, 128, 0, Wgth, Wgtl, 128, 0,
       vall, nullptr, nullptr, 128, 0, bg, 0, 2*Bg, 128, 128, 1, 1, 0, 1, 1);

  // ---- cell MLP ----
  l2norm_split_k<<<Bg, 256, 0, stream>>>(cell, 954, 960, cnh, cnl);
  gemm(cnh, cnl, 960, 0, Wr1th, Wr1tl, 960, 0, nullptr, c1h, c1l, 2048, 0,
       br1, 0, Bg, 2048, 960, 1, 1, 1, 1, 1);
  gemm(c1h, c1l, 2048, 0, Wr2th, Wr2tl, 2048, 0, c2f, nullptr, nullptr, 512, 0,
       br2, 0, Bg, 512, 2048, 1, 0, 2, 4, 1);
  act_split_k<<<((Bg*512) + 255)/256, 256, 0, stream>>>(c2f, c2h, c2l, Bg*512);
  gemm(c2h, c2l, 512, 0, Wr3th, Wr3tl, 512, 0, c3, nullptr, nullptr, 256, 0,
       br3, 0, Bg, 256, 512, 1, 1, 0, 1, 1);

  // ---- final MLP ----
  catnorm_k<<<Bg, 256, 0, stream>>>(vall, c3, xcnh, xcnl, Bg);
  gemm(xcnh, xcnl, 512, 0, Wf1th, Wf1tl, 512, 0, nullptr, t1h, t1l, 1024, 0,
       bf1, 0, Bg, 1024, 512, 1, 1, 1, 1, 1);
  gemm(t1h, t1l, 1024, 0, Wf2th, Wf2tl, 1024, 0, nullptr, t2h, t2l, 512, 0,
       bf2, 0, Bg, 512, 1024, 1, 1, 1, 1, 1);
  gemm(t2h, t2l, 512, 0, Wf3th, Wf3tl, 512, 0, nullptr, t3h, t3l, 128, 0,
       bf3, 0, Bg, 128, 512, 1, 1, 1, 1, 1);
  gemm(t3h, t3l, 128, 0, Woth, Wotl, 128, 0, out, nullptr, nullptr, 2, 0,
       bo, 0, Bg, 2, 128, 1, 0, 0, 1, 1);
}

// Round 14
// 593.347 us; speedup vs baseline: 1.0774x; 1.0774x over previous
//
#include <hip/hip_runtime.h>
#include <math.h>

typedef unsigned short ushort_t;
typedef __attribute__((ext_vector_type(8))) short short8;
typedef __attribute__((ext_vector_type(8))) unsigned short ushort8v;
typedef __attribute__((ext_vector_type(4))) float float4v;
typedef __attribute__((ext_vector_type(4))) unsigned short ushort4v;

#define MPAD 30016
#define H1STR 136

// ---------------- utility ----------------
__device__ __forceinline__ float lrelu02(float v){ return v > 0.f ? v : 0.2f*v; }
__device__ __forceinline__ float elu_fast(float v){ return v > 0.f ? v : (__expf(v) - 1.f); }

__device__ __forceinline__ ushort_t f2bf(float x){
  unsigned u = __float_as_uint(x);
  return (ushort_t)((u + 0x7fffu + ((u >> 16) & 1u)) >> 16);
}
__device__ __forceinline__ float bf2f(ushort_t h){ return __uint_as_float(((unsigned)h) << 16); }

// monotone float<->unsigned for atomicMax pooling
__device__ __forceinline__ unsigned encf(float f){
  unsigned u = __float_as_uint(f);
  return (u & 0x80000000u) ? ~u : (u | 0x80000000u);
}
__device__ __forceinline__ float decf(unsigned u){
  return __uint_as_float((u >> 31) ? (u & 0x7FFFFFFFu) : ~u);
}

__device__ __forceinline__ void gll16(const void* g, void* l){
  __builtin_amdgcn_global_load_lds((const __attribute__((address_space(1))) void*)g,
                                   (__attribute__((address_space(3))) void*)l, 16, 0, 0);
}

// ---------------- batched CSR build (both branches) ----------------
__global__ void hist2_k(const int* __restrict__ ei1, const int* __restrict__ ei2,
                        int E, int N, int* deg){
  int idx = blockIdx.x*blockDim.x + threadIdx.x;
  if (idx < 2*E){
    int br = idx / E, e = idx - br*E;
    const int* ei = br ? ei2 : ei1;
    atomicAdd(&deg[br*N + ei[E + e]], 1);
  }
}

__global__ __launch_bounds__(1024)
void scanA_k(const int* __restrict__ deg, int* __restrict__ rowptr, int* __restrict__ bsum, int n){
  int br = blockIdx.y;
  int t = threadIdx.x;
  int i = blockIdx.x*1024 + t;
  __shared__ int s[1024];
  int v = (i < n) ? (deg[br*n + i] + 1) : 0;   // +1 = self-loop
  s[t] = v; __syncthreads();
  for (int off = 1; off < 1024; off <<= 1){
    int x = (t >= off) ? s[t - off] : 0;
    __syncthreads();
    s[t] += x;
    __syncthreads();
  }
  if (i < n) rowptr[br*(n+1) + i] = s[t] - v;
  if (t == 1023) bsum[br*gridDim.x + blockIdx.x] = s[1023];
}

__global__ void scanB_k(int* bsum, int nb){
  int br = threadIdx.x;
  if (br < 2){
    int run = 0;
    for (int i = 0; i < nb; ++i){ int v = bsum[br*nb + i]; bsum[br*nb + i] = run; run += v; }
  }
}

__global__ __launch_bounds__(1024)
void scanC_k(const int* __restrict__ bsum, int* __restrict__ rowptr, int* __restrict__ cursor,
             int n, int nb, int total){
  int br = blockIdx.y;
  int i = blockIdx.x*1024 + threadIdx.x;
  int add = bsum[br*nb + blockIdx.x];
  if (i < n){
    int nv = rowptr[br*(n+1) + i] + add;
    rowptr[br*(n+1) + i] = nv;
    cursor[br*n + i] = nv;
  }
  if (i == 0) rowptr[br*(n+1) + n] = total;
}

// edges + self-loops in one pass (order within a row irrelevant)
__global__ void fill_csr2_k(const int* __restrict__ ei1, const int* __restrict__ ei2,
                            int E, int N, int* cursor, int* csr){
  int idx = blockIdx.x*blockDim.x + threadIdx.x;
  if (idx < 2*E){
    int br = idx / E, e = idx - br*E;
    const int* ei = br ? ei2 : ei1;
    int dst = ei[E + e];
    int pos = atomicAdd(&cursor[br*N + dst], 1);
    csr[br*(E+N) + pos] = ei[e];
  } else if (idx < 2*E + 2*N){
    int r = idx - 2*E;
    int br = r / N, i = r - br*N;
    int pos = atomicAdd(&cursor[br*N + i], 1);
    csr[br*(E+N) + pos] = i;
  }
}

// ---------------- attention score precompute (merged) ----------------
__global__ void mkattn_k(const float* __restrict__ W1, const float* __restrict__ a_src1,
                         const float* __restrict__ a_dst1,
                         const float* __restrict__ W2, const float* __restrict__ a_src2,
                         const float* __restrict__ a_dst2,
                         float* As, float* Ad, float* vs, float* vd){
  int idx = blockIdx.x*blockDim.x + threadIdx.x;
  if (idx < 780){
    int f = idx / 10, h = idx % 10;
    float ss = 0.f, sd = 0.f;
    for (int c = 0; c < 128; ++c){
      float w = W1[f*1280 + h*128 + c];
      ss += w * a_src1[h*128 + c];
      sd += w * a_dst1[h*128 + c];
    }
    As[idx] = ss; Ad[idx] = sd;
  } else if (idx < 2060){
    int k = idx - 780;
    float ss = 0.f, sd = 0.f;
    for (int c = 0; c < 128; ++c){
      float w = W2[k*128 + c];
      ss += w * a_src2[c]; sd += w * a_dst2[c];
    }
    vs[k] = ss; vd[k] = sd;
  }
}

// node-per-thread alpha1 (both branches); As/Ad staged in LDS
__global__ __launch_bounds__(256)
void alpha1b_k(const float* __restrict__ x1, const float* __restrict__ x2,
               const float* __restrict__ As, const float* __restrict__ Ad,
               float* as1, float* ad1, int n){
  __shared__ float sAs[780], sAd[780];
  int t = threadIdx.x;
  for (int k = t; k < 780; k += 256){ sAs[k] = As[k]; sAd[k] = Ad[k]; }
  __syncthreads();
  int idx = blockIdx.x*256 + t;
  if (idx >= 2*n) return;
  int br = idx / n, i = idx - br*n;
  const float* xr = (br ? x2 : x1) + (size_t)i*78;
  float ss[10], sd[10];
  #pragma unroll
  for (int h = 0; h < 10; ++h){ ss[h] = 0.f; sd[h] = 0.f; }
  for (int f = 0; f < 78; ++f){
    float xv = xr[f];
    #pragma unroll
    for (int h = 0; h < 10; ++h){
      ss[h] += xv * sAs[f*10 + h];
      sd[h] += xv * sAd[f*10 + h];
    }
  }
  #pragma unroll
  for (int h = 0; h < 10; ++h){
    as1[(size_t)idx*10 + h] = ss[h];
    ad1[(size_t)idx*10 + h] = sd[h];
  }
}

// ---------------- GATConv1 one-pass softmax + aggregate (both branches) ----------------
__global__ __launch_bounds__(64)
void gat1_agg_k(const int* __restrict__ rowptr2, const int* __restrict__ csr2,
                const float* __restrict__ x1, const float* __restrict__ x2,
                const float* __restrict__ as1b, const float* __restrict__ ad1b,
                ushort_t* __restrict__ yh, int n, int E){
  int gi = blockIdx.x;
  int br = (gi >= n) ? 1 : 0;
  int i = gi - br*n;
  int t = threadIdx.x;
  const int* rowptr = rowptr2 + (size_t)br*(n+1);
  const int* csr    = csr2 + (size_t)br*(E+n);
  const float* x    = br ? x2 : x1;
  const float* as1  = as1b + (size_t)br*n*10;
  ushort_t* yb      = yh + (size_t)br*10*MPAD*96;

  __shared__ float adi[10], rden[10], wE[10], xs[78];
  int beg = rowptr[i], end = rowptr[i+1];
  if (t < 10) adi[t] = ad1b[(size_t)gi*10 + t];
  __syncthreads();
  float den = 0.f;
  float acc[13];
  int hh[13], cc[13];
  #pragma unroll
  for (int k = 0; k < 13; ++k){
    acc[k] = 0.f;
    int j = t + 64*k;
    hh[k] = (j < 780) ? (j/78) : 0;
    cc[k] = (j < 780) ? (j%78) : 0;
  }
  for (int e = beg; e < end; ++e){
    int s = csr[e];
    if (t < 10){
      float w = __expf(lrelu02(as1[(size_t)s*10 + t] + adi[t]));
      wE[t] = w; den += w;
    }
    for (int c = t; c < 78; c += 64) xs[c] = x[(size_t)s*78 + c];
    __syncthreads();
    #pragma unroll
    for (int k = 0; k < 13; ++k){
      int j = t + 64*k;
      if (j < 780) acc[k] += wE[hh[k]] * xs[cc[k]];
    }
    __syncthreads();
  }
  if (t < 10) rden[t] = 1.f/(den + 1e-16f);
  __syncthreads();
  #pragma unroll
  for (int k = 0; k < 13; ++k){
    int j = t + 64*k;
    if (j < 780) yb[((size_t)hh[k]*MPAD + i)*96 + cc[k]] = f2bf(acc[k]*rden[hh[k]]);
  }
  for (int p = t; p < 180; p += 64){
    int h = p/18, c = 78 + p%18;
    yb[((size_t)h*MPAD + i)*96 + c] = 0;
  }
}

// ---------------- fused branch conv (direct-load GEMMs; LDS only for h1t) ----------------
// A/B fragments loaded global->VGPR (W1h/W2h are L2-resident; y streamed).
// 2 barriers per head. 18.4 KB LDS. NO min-wave clamp: let allocator use ~170 VGPR.
__global__ __launch_bounds__(256)
void branch_conv_k(const ushort_t* __restrict__ yall,
                   const ushort_t* __restrict__ W1h, const ushort_t* __restrict__ W2h,
                   const float* __restrict__ b1, const float* __restrict__ vs,
                   const float* __restrict__ vd,
                   ushort_t* __restrict__ h2all, float* __restrict__ as2all,
                   float* __restrict__ ad2all, int M){
  const int NBLK = MPAD/64;
  int br = blockIdx.x / NBLK;
  int bi = blockIdx.x - br*NBLK;
  const ushort_t* y = yall + (size_t)br*10*MPAD*96;
  ushort_t* h2 = h2all + (size_t)br*MPAD*128;
  float* as2 = as2all + (size_t)br*MPAD;
  float* ad2 = ad2all + (size_t)br*MPAD;

  __shared__ __align__(16) ushort_t h1t[64*H1STR];   // 17408 B
  __shared__ float red[256];

  int tid = threadIdx.x, lane = tid & 63, wave = tid >> 6;
  int row0 = bi*64;
  int wm = (wave & 1)*32, wn = (wave >> 1)*64;
  int lr = lane & 15, quad = lane >> 4;

  float4v acc2[2][4];
  #pragma unroll
  for (int i = 0; i < 2; ++i)
    #pragma unroll
    for (int j = 0; j < 4; ++j)
      acc2[i][j] = (float4v){0.f, 0.f, 0.f, 0.f};
  float rps[8], rpd[8];
  #pragma unroll
  for (int z = 0; z < 8; ++z){ rps[z] = 0.f; rpd[z] = 0.f; }

  for (int h = 0; h < 10; ++h){
    // ---- P1: h1e_h = y_h @ W1_h (K=96), fragments direct from global ----
    float4v acc1[2][4];
    #pragma unroll
    for (int i = 0; i < 2; ++i)
      #pragma unroll
      for (int j = 0; j < 4; ++j)
        acc1[i][j] = (float4v){0.f, 0.f, 0.f, 0.f};
    #pragma unroll
    for (int it = 0; it < 3; ++it){
      short8 af[2], bf[4];
      #pragma unroll
      for (int t2 = 0; t2 < 2; ++t2)
        af[t2] = *(const short8*)&y[((size_t)h*MPAD + row0 + wm + t2*16 + lr)*96 + it*32 + quad*8];
      #pragma unroll
      for (int j = 0; j < 4; ++j)
        bf[j] = *(const short8*)&W1h[((size_t)(h*128 + wn + j*16 + lr))*96 + it*32 + quad*8];
      #pragma unroll
      for (int i = 0; i < 2; ++i)
        #pragma unroll
        for (int j = 0; j < 4; ++j)
          acc1[i][j] = __builtin_amdgcn_mfma_f32_16x16x32_bf16(af[i], bf[j], acc1[i][j], 0, 0, 0);
    }

    // ---- ELU + bias; write h1t; accumulate alpha2 from fp32 values ----
    #pragma unroll
    for (int j = 0; j < 4; ++j){
      int col = wn + j*16 + lr;
      float bv  = b1[h*128 + col];
      float vsv = vs[h*128 + col];
      float vdv = vd[h*128 + col];
      #pragma unroll
      for (int i = 0; i < 2; ++i){
        #pragma unroll
        for (int r = 0; r < 4; ++r){
          float v = elu_fast(acc1[i][j][r] + bv);
          h1t[(wm + i*16 + quad*4 + r)*H1STR + col] = f2bf(v);
          rps[i*4 + r] += v * vsv;
          rpd[i*4 + r] += v * vdv;
        }
      }
    }
    __syncthreads();   // h1t visible to all waves

    // ---- P2: h2 += h1t @ W2[h*128:(h+1)*128, :] (K=128); B direct from global ----
    #pragma unroll
    for (int it = 0; it < 4; ++it){
      int kt = it*32;
      short8 af[2], bf[4];
      #pragma unroll
      for (int t2 = 0; t2 < 2; ++t2)
        af[t2] = *(const short8*)&h1t[(wm + t2*16 + lr)*H1STR + kt + quad*8];
      #pragma unroll
      for (int j = 0; j < 4; ++j)
        bf[j] = *(const short8*)&W2h[((size_t)(wn + j*16 + lr))*1280 + h*128 + kt + quad*8];
      #pragma unroll
      for (int i = 0; i < 2; ++i)
        #pragma unroll
        for (int j = 0; j < 4; ++j)
          acc2[i][j] = __builtin_amdgcn_mfma_f32_16x16x32_bf16(af[i], bf[j], acc2[i][j], 0, 0, 0);
    }
    __syncthreads();   // h1t reads done before next head overwrites
  }

  // ---- h2 store (bf16) ----
  #pragma unroll
  for (int j = 0; j < 4; ++j){
    int col = wn + j*16 + lr;
    #pragma unroll
    for (int i = 0; i < 2; ++i){
      #pragma unroll
      for (int r = 0; r < 4; ++r){
        int row = row0 + wm + i*16 + quad*4 + r;
        if (row < M) h2[(size_t)row*128 + col] = f2bf(acc2[i][j][r]);
      }
    }
  }
  // ---- alpha2 reduce ----
  __syncthreads();
  #pragma unroll
  for (int z = 0; z < 8; ++z){
    float a = rps[z], d = rpd[z];
    #pragma unroll
    for (int mk = 1; mk <= 8; mk <<= 1){
      a += __shfl_xor(a, mk);
      d += __shfl_xor(d, mk);
    }
    if (lr == 0){
      int i = z >> 2, r = z & 3;
      int row = wm + i*16 + quad*4 + r;
      red[row*2 + (wave >> 1)] = a;
      red[128 + row*2 + (wave >> 1)] = d;
    }
  }
  __syncthreads();
  if (tid < 64){
    int grow = row0 + tid;
    if (grow < M){
      as2[grow] = red[tid*2] + red[tid*2 + 1];
      ad2[grow] = red[128 + tid*2] + red[128 + tid*2 + 1];
    }
  }
}

// ---------------- GATConv2 one-pass softmax + aggregate + atomic pool (bf16 h2) ----------------
__global__ __launch_bounds__(64)
void gat2_agg_k(const int* __restrict__ rowptr2, const int* __restrict__ csr2,
                const ushort_t* __restrict__ h2all, const float* __restrict__ as2all,
                const float* __restrict__ ad2all, const float* __restrict__ b2,
                const int* __restrict__ batch1, const int* __restrict__ batch2,
                unsigned* __restrict__ poolKey, int n, int E, int Bg){
  int gi = blockIdx.x;
  int br = (gi >= n) ? 1 : 0;
  int i = gi - br*n;
  int t = threadIdx.x;
  const int* rowptr = rowptr2 + (size_t)br*(n+1);
  const int* csr    = csr2 + (size_t)br*(E+n);
  const ushort_t* h2 = h2all + (size_t)br*MPAD*128;
  const float* as2  = as2all + (size_t)br*MPAD;
  float adi = ad2all[(size_t)br*MPAD + i];
  int beg = rowptr[i], end = rowptr[i+1];
  float den = 0.f, a0 = 0.f, a1 = 0.f;
  for (int e = beg; e < end; ++e){
    int s = csr[e];
    float w = __expf(lrelu02(as2[s] + adi));
    den += w;
    unsigned u = *(const unsigned*)&h2[(size_t)s*128 + 2*t];
    a0 += w * bf2f((ushort_t)(u & 0xffffu));
    a1 += w * bf2f((ushort_t)(u >> 16));
  }
  float r = 1.f/(den + 1e-16f);
  float o0 = elu_fast(a0*r + b2[2*t]);
  float o1 = elu_fast(a1*r + b2[2*t + 1]);
  int g = (br ? batch2 : batch1)[i];
  unsigned* pk = poolKey + ((size_t)br*Bg + g)*128;
  atomicMax(&pk[2*t], encf(o0));
  atomicMax(&pk[2*t + 1], encf(o1));
}

// ---------------- pool decode → split bf16 ----------------
__global__ void pool_decode_k(const unsigned* __restrict__ key,
                              ushort_t* __restrict__ ph, ushort_t* __restrict__ pl, int n){
  int i = blockIdx.x*blockDim.x + threadIdx.x;
  if (i < n){
    float v = decf(key[i]);
    ushort_t h = f2bf(v);
    ph[i] = h; pl[i] = f2bf(v - bf2f(h));
  }
}

// ---------------- row-wise L2 normalize → split bf16 (K-padded) ----------------
__global__ __launch_bounds__(256)
void l2norm_split_k(const float* __restrict__ in, int cols, int Kp,
                    ushort_t* __restrict__ oh, ushort_t* __restrict__ ol){
  int r = blockIdx.x, t = threadIdx.x;
  __shared__ float s[256];
  __shared__ float scaleS;
  const float* rp = in + (size_t)r*cols;
  float p = 0.f;
  for (int k = t; k < cols; k += 256){ float v = rp[k]; p += v*v; }
  s[t] = p; __syncthreads();
  for (int o = 128; o > 0; o >>= 1){
    if (t < o) s[t] += s[t+o];
    __syncthreads();
  }
  if (t == 0) scaleS = 1.f / fmaxf(sqrtf(s[0]), 1e-12f);
  __syncthreads();
  float sc = scaleS;
  for (int k = t; k < Kp; k += 256){
    float v = (k < cols) ? rp[k]*sc : 0.f;
    ushort_t h = f2bf(v);
    size_t o2 = (size_t)r*Kp + k;
    oh[o2] = h; ol[o2] = f2bf(v - bf2f(h));
  }
}

// ---------------- fused concat + l2norm + split ----------------
__global__ __launch_bounds__(256)
void catnorm_k(const float* __restrict__ vall, const float* __restrict__ c3,
               ushort_t* __restrict__ oh, ushort_t* __restrict__ ol, int Bg){
  int r = blockIdx.x, t = threadIdx.x;
  __shared__ float s[256];
  __shared__ float scaleS;
  auto val = [&](int c)->float{
    if (c < 128) return vall[(size_t)r*128 + c];
    if (c < 256) return vall[((size_t)Bg + r)*128 + (c - 128)];
    return c3[(size_t)r*256 + (c - 256)];
  };
  float v0 = val(t), v1 = val(t + 256);
  s[t] = v0*v0 + v1*v1; __syncthreads();
  for (int o = 128; o > 0; o >>= 1){
    if (t < o) s[t] += s[t+o];
    __syncthreads();
  }
  if (t == 0) scaleS = 1.f / fmaxf(sqrtf(s[0]), 1e-12f);
  __syncthreads();
  float sc = scaleS;
  float a = v0*sc, b = v1*sc;
  ushort_t ha = f2bf(a), hb = f2bf(b);
  size_t o2 = (size_t)r*512;
  oh[o2 + t] = ha;       ol[o2 + t] = f2bf(a - bf2f(ha));
  oh[o2 + 256 + t] = hb; ol[o2 + 256 + t] = f2bf(b - bf2f(hb));
}

// relu + split (post split-K reduction)
__global__ void act_split_k(const float* __restrict__ in, ushort_t* __restrict__ oh,
                            ushort_t* __restrict__ ol, int n){
  int i = blockIdx.x*blockDim.x + threadIdx.x;
  if (i < n){
    float v = fmaxf(in[i], 0.f);
    ushort_t h = f2bf(v);
    oh[i] = h; ol[i] = f2bf(v - bf2f(h));
  }
}

// ---------------- merged weight transpose + split ----------------
__device__ __forceinline__ void split_one(const float* __restrict__ W, int ldw, int colStride,
                                          int N, int K, int Np, int Kp,
                                          ushort_t* __restrict__ dh, ushort_t* __restrict__ dl,
                                          int idx){
  int n  = idx % Np;
  int r  = idx / Np;
  int k4 = r % (Kp >> 2);
  int b  = r / (Kp >> 2);
  size_t o = ((size_t)b*Np + n)*Kp + (size_t)k4*4;
  ushort4v hv, lv;
  #pragma unroll
  for (int kk = 0; kk < 4; ++kk){
    int k = k4*4 + kk;
    float v = (n < N && k < K) ? W[(size_t)k*ldw + (size_t)b*colStride + n] : 0.f;
    ushort_t h = f2bf(v);
    hv[kk] = h; lv[kk] = f2bf(v - bf2f(h));
  }
  *(ushort4v*)&dh[o] = hv;
  if (dl) *(ushort4v*)&dl[o] = lv;
}

struct SplitTable {
  const float *W1, *W2, *Wg, *Wr1, *Wr2, *Wr3, *Wf1, *Wf2, *Wf3, *Wo;
  ushort_t *W1h,*W2h,*Wgh,*Wgl,*Wr1h,*Wr1l,*Wr2h,*Wr2l;
  ushort_t *Wr3h,*Wr3l,*Wf1h,*Wf1l,*Wf2h,*Wf2l,*Wf3h,*Wf3l,*Woh,*Wol;
};

__global__ void split_all_k(SplitTable T){
  int idx = blockIdx.x*blockDim.x + threadIdx.x;
  if      (idx <   30720) split_one(T.W1, 1280, 128, 128,   78,  128,   96, T.W1h, nullptr, idx);
  else if (idx <   71680) split_one(T.W2,  128,   0, 128, 1280,  128, 1280, T.W2h, nullptr, idx -   30720);
  else if (idx <   75776) split_one(T.Wg,  128,   0, 128,  128,  128,  128, T.Wgh, T.Wgl, idx -   71680);
  else if (idx <  567296) split_one(T.Wr1,2048,   0,2048,  954, 2048,  960, T.Wr1h,T.Wr1l,idx -   75776);
  else if (idx <  829440) split_one(T.Wr2, 512,   0, 512, 2048,  512, 2048, T.Wr2h,T.Wr2l,idx -  567296);
  else if (idx <  862208) split_one(T.Wr3, 256,   0, 256,  512,  256,  512, T.Wr3h,T.Wr3l,idx -  829440);
  else if (idx <  993280) split_one(T.Wf1,1024,   0,1024,  512, 1024,  512, T.Wf1h,T.Wf1l,idx -  862208);
  else if (idx < 1124352) split_one(T.Wf2, 512,   0, 512, 1024,  512, 1024, T.Wf2h,T.Wf2l,idx -  993280);
  else if (idx < 1140736) split_one(T.Wf3, 128,   0, 128,  512,  128,  512, T.Wf3h,T.Wf3l,idx - 1124352);
  else if (idx < 1142784) split_one(T.Wo,    2,   0,   2,  128,   64,  128, T.Woh, T.Wol, idx - 1140736);
}

// ---------------- split-bf16 MFMA GEMM (MLP path) ----------------
__global__ __launch_bounds__(256)
void gemm_split(const ushort_t* __restrict__ Ahp, const ushort_t* __restrict__ Alp, int lda, long long sA,
                const ushort_t* __restrict__ Bhp, const ushort_t* __restrict__ Blp, int ldb, long long sB,
                float* __restrict__ C, ushort_t* __restrict__ Ch, ushort_t* __restrict__ Cl,
                int ldc, long long sC,
                const float* __restrict__ bias, int sBias,
                int M, int Nc, int K, int act, int outMode, int kSplit, int aSplit){
  int zb = blockIdx.z;
  int b = zb / kSplit, kc = zb - b*kSplit;
  Ahp += (long long)b*sA;
  Bhp += (long long)b*sB; Blp += (long long)b*sB;
  long long cOff = (long long)b*sC;
  int Kc = K / kSplit;
  int kb = kc*Kc;
  int nIter = Kc / 32;

  __shared__ ushort_t smem[18048];

  int tid = threadIdx.x, lane = tid & 63, wave = tid >> 6;
  int row0 = blockIdx.y*64, col0 = blockIdx.x*64;
  int wm = (wave & 1)*32, wn = (wave >> 1)*32;
  int lr = lane & 15, quad = lane >> 4;
  int qs = (quad ^ ((lr >> 1) & 3)) * 8;

  int srow = wave*16 + (lane >> 2);
  int skc  = (((lane & 3) ^ ((lane >> 3) & 3)) * 8);
  const ushort_t* gAh = Ahp + (long long)(row0 + srow)*lda + skc + kb;
  const ushort_t* gAl = aSplit ? (Alp + (long long)b*sA + (long long)(row0 + srow)*lda + skc + kb) : gAh;
  const ushort_t* gBh = Bhp + (long long)(col0 + srow)*ldb + skc + kb;
  const ushort_t* gBl = Blp + (long long)(col0 + srow)*ldb + skc + kb;

  float4v acc[2][2];
  #pragma unroll
  for (int i = 0; i < 2; ++i)
    #pragma unroll
    for (int j = 0; j < 2; ++j)
      acc[i][j] = (float4v){0.f, 0.f, 0.f, 0.f};

  auto issue = [&](int p, int kt){
    ushort_t* base = &smem[p*8192 + wave*512];
    gll16(gAh + kt, base);
    if (aSplit) gll16(gAl + kt, base + 2048);
    gll16(gBh + kt, base + 4096);
    gll16(gBl + kt, base + 6144);
  };

  issue(0, 0);
  int p = 0;
  for (int it = 0; it < nIter; ++it){
    __syncthreads();
    if (it + 1 < nIter) issue(p ^ 1, (it + 1)*32);
    const ushort_t* sm = &smem[p*8192];
    short8 ah[2], al[2], bh[2], bl[2];
    #pragma unroll
    for (int t2 = 0; t2 < 2; ++t2){
      int ao = (wm + t2*16 + lr)*32 + qs;
      int bo = (wn + t2*16 + lr)*32 + qs;
      ah[t2] = *(const short8*)&sm[ao];
      if (aSplit) al[t2] = *(const short8*)&sm[2048 + ao];
      bh[t2] = *(const short8*)&sm[4096 + bo];
      bl[t2] = *(const short8*)&sm[6144 + bo];
    }
    #pragma unroll
    for (int i = 0; i < 2; ++i)
      #pragma unroll
      for (int j = 0; j < 2; ++j){
        if (aSplit)
          acc[i][j] = __builtin_amdgcn_mfma_f32_16x16x32_bf16(al[i], bh[j], acc[i][j], 0, 0, 0);
        acc[i][j] = __builtin_amdgcn_mfma_f32_16x16x32_bf16(ah[i], bl[j], acc[i][j], 0, 0, 0);
        acc[i][j] = __builtin_amdgcn_mfma_f32_16x16x32_bf16(ah[i], bh[j], acc[i][j], 0, 0, 0);
      }
    p ^= 1;
  }
  __syncthreads();

  if (outMode == 0 || outMode == 2){
    #pragma unroll
    for (int j = 0; j < 2; ++j){
      int col = col0 + wn + j*16 + lr;
      if (col >= Nc) continue;
      float bv = (bias && kc == 0) ? bias[(long long)b*sBias + col] : 0.f;
      #pragma unroll
      for (int i = 0; i < 2; ++i){
        #pragma unroll
        for (int r = 0; r < 4; ++r){
          int row = row0 + wm + i*16 + quad*4 + r;
          if (row >= M) continue;
          float v = acc[i][j][r] + bv;
          if (act == 1) v = fmaxf(v, 0.f);
          else if (act == 2) v = elu_fast(v);
          long long o = cOff + (long long)row*ldc + col;
          if (outMode == 0) C[o] = v;
          else atomicAdd(&C[o], v);
        }
      }
    }
  } else {
    float* ftile = (float*)smem;
    #pragma unroll
    for (int i = 0; i < 2; ++i)
      #pragma unroll
      for (int j = 0; j < 2; ++j)
        #pragma unroll
        for (int r = 0; r < 4; ++r)
          ftile[(wm + i*16 + quad*4 + r)*68 + wn + j*16 + lr] = acc[i][j][r];
    __syncthreads();
    int row = tid >> 2, ch = (tid & 3)*16;
    int grow = row0 + row;
    if (grow < M){
      if (col0 + 64 <= Nc){
        long long o = cOff + (long long)grow*ldc + col0 + ch;
        #pragma unroll
        for (int g = 0; g < 2; ++g){
          ushort8v hv, lv;
          #pragma unroll
          for (int c = 0; c < 8; ++c){
            int cc2 = ch + g*8 + c;
            float v = ftile[row*68 + cc2];
            if (bias) v += bias[(long long)b*sBias + col0 + cc2];
            if (act == 1) v = fmaxf(v, 0.f);
            else if (act == 2) v = elu_fast(v);
            hv[c] = f2bf(v);
            lv[c] = f2bf(v - bf2f(hv[c]));
          }
          *(ushort8v*)&Ch[o + g*8] = hv;
          *(ushort8v*)&Cl[o + g*8] = lv;
        }
      } else {
        for (int c = 0; c < 16; ++c){
          int col = col0 + ch + c;
          if (col >= Nc) break;
          float v = ftile[row*68 + ch + c];
          if (bias) v += bias[(long long)b*sBias + col];
          if (act == 1) v = fmaxf(v, 0.f);
          else if (act == 2) v = elu_fast(v);
          long long o = cOff + (long long)grow*ldc + col;
          ushort_t h = f2bf(v);
          Ch[o] = h;
          Cl[o] = f2bf(v - bf2f(h));
        }
      }
    }
  }
}

// ---------------- host launch ----------------
extern "C" void kernel_launch(void* const* d_in, const int* in_sizes, int n_in,
                              void* d_out, int out_size, void* d_ws, size_t ws_size,
                              hipStream_t stream){
  const float* x1     = (const float*)d_in[0];
  const int*   ei1    = (const int*)  d_in[1];
  const int*   batch1 = (const int*)  d_in[2];
  const float* x2     = (const float*)d_in[3];
  const int*   ei2    = (const int*)  d_in[4];
  const int*   batch2 = (const int*)  d_in[5];
  const float* cell   = (const float*)d_in[6];
  const float* W1     = (const float*)d_in[7];
  const float* a_src1 = (const float*)d_in[8];
  const float* a_dst1 = (const float*)d_in[9];
  const float* b1     = (const float*)d_in[10];
  const float* W2     = (const float*)d_in[11];
  const float* a_src2 = (const float*)d_in[12];
  const float* a_dst2 = (const float*)d_in[13];
  const float* b2     = (const float*)d_in[14];
  const float* Wg     = (const float*)d_in[15];
  const float* bg     = (const float*)d_in[16];
  const float* Wr1    = (const float*)d_in[17];
  const float* br1    = (const float*)d_in[18];
  const float* Wr2    = (const float*)d_in[19];
  const float* br2    = (const float*)d_in[20];
  const float* Wr3    = (const float*)d_in[21];
  const float* br3    = (const float*)d_in[22];
  const float* Wf1    = (const float*)d_in[23];
  const float* bf1    = (const float*)d_in[24];
  const float* Wf2    = (const float*)d_in[25];
  const float* bf2    = (const float*)d_in[26];
  const float* Wf3    = (const float*)d_in[27];
  const float* bf3    = (const float*)d_in[28];
  const float* Wo     = (const float*)d_in[29];
  const float* bo     = (const float*)d_in[30];
  float* out = (float*)d_out;
  (void)n_in; (void)out_size; (void)ws_size;

  const int N  = in_sizes[0] / 78;
  const int E  = in_sizes[1] / 2;
  const int Bg = in_sizes[6] / 954;

  char* wsb = (char*)d_ws;
  size_t off = 0;
  auto alloc = [&](size_t bytes)->char*{
    char* p = wsb + off; off += ((bytes + 255)/256)*256; return p;
  };

  // Y region: yh (both branches) during branch phase; MLP bufs alias after
  char* Yb = alloc((size_t)2*10*MPAD*96*2);
  ushort_t* yh = (ushort_t*)Yb;
  size_t yoff = 0;
  auto yalloc = [&](size_t bytes)->char*{
    char* p = Yb + yoff; yoff += ((bytes + 255)/256)*256; return p;
  };
  ushort_t* cnh  = (ushort_t*)yalloc((size_t)Bg*960*2);
  ushort_t* cnl  = (ushort_t*)yalloc((size_t)Bg*960*2);
  ushort_t* c1h  = (ushort_t*)yalloc((size_t)Bg*2048*2);
  ushort_t* c1l  = (ushort_t*)yalloc((size_t)Bg*2048*2);
  ushort_t* c2h  = (ushort_t*)yalloc((size_t)Bg*512*2);
  ushort_t* c2l  = (ushort_t*)yalloc((size_t)Bg*512*2);
  float*    c3   = (float*)   yalloc((size_t)Bg*256*4);
  ushort_t* xcnh = (ushort_t*)yalloc((size_t)Bg*512*2);
  ushort_t* xcnl = (ushort_t*)yalloc((size_t)Bg*512*2);
  ushort_t* t1h  = (ushort_t*)yalloc((size_t)Bg*1024*2);
  ushort_t* t1l  = (ushort_t*)yalloc((size_t)Bg*1024*2);
  ushort_t* t2h  = (ushort_t*)yalloc((size_t)Bg*512*2);
  ushort_t* t2l  = (ushort_t*)yalloc((size_t)Bg*512*2);
  ushort_t* t3h  = (ushort_t*)yalloc((size_t)Bg*128*2);
  ushort_t* t3l  = (ushort_t*)yalloc((size_t)Bg*128*2);
  ushort_t* pooledh = (ushort_t*)yalloc((size_t)2*Bg*128*2);
  ushort_t* pooledl = (ushort_t*)yalloc((size_t)2*Bg*128*2);
  float*    vall    = (float*)   yalloc((size_t)2*Bg*128*4);

  // zero-init region (single memset): c2f, poolKey, deg2
  size_t zElems = (size_t)Bg*512 + (size_t)2*Bg*128 + (size_t)2*N;
  float* zbase = (float*)alloc(zElems*4);
  float* c2f = zbase;
  unsigned* poolKey = (unsigned*)(c2f + (size_t)Bg*512);
  int* deg2 = (int*)(poolKey + (size_t)2*Bg*128);

  ushort_t* h2 = (ushort_t*)alloc((size_t)2*MPAD*128*2);
  float* as2 = (float*)alloc((size_t)2*MPAD*4);
  float* ad2 = (float*)alloc((size_t)2*MPAD*4);

  // transposed weights: W1/W2 hi-only; MLP weights split
  ushort_t* W1th = (ushort_t*)alloc((size_t)10*128*96*2);
  ushort_t* W2th = (ushort_t*)alloc((size_t)128*1280*2);
  ushort_t* Wgth = (ushort_t*)alloc((size_t)128*128*2);
  ushort_t* Wgtl = (ushort_t*)alloc((size_t)128*128*2);
  ushort_t* Wr1th= (ushort_t*)alloc((size_t)2048*960*2);
  ushort_t* Wr1tl= (ushort_t*)alloc((size_t)2048*960*2);
  ushort_t* Wr2th= (ushort_t*)alloc((size_t)512*2048*2);
  ushort_t* Wr2tl= (ushort_t*)alloc((size_t)512*2048*2);
  ushort_t* Wr3th= (ushort_t*)alloc((size_t)256*512*2);
  ushort_t* Wr3tl= (ushort_t*)alloc((size_t)256*512*2);
  ushort_t* Wf1th= (ushort_t*)alloc((size_t)1024*512*2);
  ushort_t* Wf1tl= (ushort_t*)alloc((size_t)1024*512*2);
  ushort_t* Wf2th= (ushort_t*)alloc((size_t)512*1024*2);
  ushort_t* Wf2tl= (ushort_t*)alloc((size_t)512*1024*2);
  ushort_t* Wf3th= (ushort_t*)alloc((size_t)128*512*2);
  ushort_t* Wf3tl= (ushort_t*)alloc((size_t)128*512*2);
  ushort_t* Woth = (ushort_t*)alloc((size_t)64*128*2);
  ushort_t* Wotl = (ushort_t*)alloc((size_t)64*128*2);

  float* as1b = (float*)alloc((size_t)2*N*10*4);
  float* ad1b = (float*)alloc((size_t)2*N*10*4);
  float* AsB  = (float*)alloc(780*4);
  float* AdB  = (float*)alloc(780*4);
  float* vs   = (float*)alloc(1280*4);
  float* vd   = (float*)alloc(1280*4);
  int* rowptr2 = (int*)alloc((size_t)2*(N+1)*4);
  int* cursor2 = (int*)alloc((size_t)2*N*4);
  int* csr2    = (int*)alloc((size_t)2*(E+N)*4);
  int* bsum    = (int*)alloc((size_t)2*64*4);

  auto gemm = [&](const ushort_t* Ah_, const ushort_t* Al_, int lda, long long sA_,
                  const ushort_t* Bh_, const ushort_t* Bl_, int ldb, long long sB_,
                  float* C_, ushort_t* Ch_, ushort_t* Cl_, int ldc, long long sC_,
                  const float* bias_, int sBias_, int M_, int N_, int K_, int batch_,
                  int act_, int mode_, int kSplit_, int aSplit_){
    dim3 grid((N_ + 63)/64, (M_ + 63)/64, batch_*kSplit_);
    gemm_split<<<grid, 256, 0, stream>>>(Ah_, Al_, lda, sA_, Bh_, Bl_, ldb, sB_,
                                         C_, Ch_, Cl_, ldc, sC_, bias_, sBias_,
                                         M_, N_, K_, act_, mode_, kSplit_, aSplit_);
  };

  // ---- init + weight prep ----
  hipMemsetAsync(zbase, 0, zElems*4, stream);
  SplitTable T;
  T.W1 = W1; T.W2 = W2; T.Wg = Wg; T.Wr1 = Wr1; T.Wr2 = Wr2; T.Wr3 = Wr3;
  T.Wf1 = Wf1; T.Wf2 = Wf2; T.Wf3 = Wf3; T.Wo = Wo;
  T.W1h = W1th; T.W2h = W2th; T.Wgh = Wgth; T.Wgl = Wgtl;
  T.Wr1h = Wr1th; T.Wr1l = Wr1tl; T.Wr2h = Wr2th; T.Wr2l = Wr2tl;
  T.Wr3h = Wr3th; T.Wr3l = Wr3tl; T.Wf1h = Wf1th; T.Wf1l = Wf1tl;
  T.Wf2h = Wf2th; T.Wf2l = Wf2tl; T.Wf3h = Wf3th; T.Wf3l = Wf3tl;
  T.Woh = Woth; T.Wol = Wotl;
  split_all_k<<<(1142784 + 255)/256, 256, 0, stream>>>(T);
  mkattn_k<<<(2060 + 255)/256, 256, 0, stream>>>(W1, a_src1, a_dst1, W2, a_src2, a_dst2,
                                                 AsB, AdB, vs, vd);
  alpha1b_k<<<((2*N) + 255)/256, 256, 0, stream>>>(x1, x2, AsB, AdB, as1b, ad1b, N);

  // ---- batched CSR build ----
  const int NB = (N + 1023)/1024;
  hist2_k<<<((2*E) + 255)/256, 256, 0, stream>>>(ei1, ei2, E, N, deg2);
  scanA_k<<<dim3(NB, 2), 1024, 0, stream>>>(deg2, rowptr2, bsum, N);
  scanB_k<<<1, 64, 0, stream>>>(bsum, NB);
  scanC_k<<<dim3(NB, 2), 1024, 0, stream>>>(bsum, rowptr2, cursor2, N, NB, E + N);
  fill_csr2_k<<<((2*E + 2*N) + 255)/256, 256, 0, stream>>>(ei1, ei2, E, N, cursor2, csr2);

  // ---- branches (batched) ----
  gat1_agg_k<<<2*N, 64, 0, stream>>>(rowptr2, csr2, x1, x2, as1b, ad1b, yh, N, E);
  branch_conv_k<<<2*(MPAD/64), 256, 0, stream>>>(yh, W1th, W2th,
                                                 b1, vs, vd, h2, as2, ad2, N);
  gat2_agg_k<<<2*N, 64, 0, stream>>>(rowptr2, csr2, h2, as2, ad2, b2,
                                     batch1, batch2, poolKey, N, E, Bg);
  pool_decode_k<<<((2*Bg*128) + 255)/256, 256, 0, stream>>>(poolKey, pooledh, pooledl, 2*Bg*128);
  gemm(pooledh, pooledl, 128, 0, Wgth, Wgtl, 128, 0,
       vall, nullptr, nullptr, 128, 0, bg, 0, 2*Bg, 128, 128, 1, 1, 0, 1, 1);

  // ---- cell MLP ----
  l2norm_split_k<<<Bg, 256, 0, stream>>>(cell, 954, 960, cnh, cnl);
  gemm(cnh, cnl, 960, 0, Wr1th, Wr1tl, 960, 0, nullptr, c1h, c1l, 2048, 0,
       br1, 0, Bg, 2048, 960, 1, 1, 1, 1, 1);
  gemm(c1h, c1l, 2048, 0, Wr2th, Wr2tl, 2048, 0, c2f, nullptr, nullptr, 512, 0,
       br2, 0, Bg, 512, 2048, 1, 0, 2, 4, 1);
  act_split_k<<<((Bg*512) + 255)/256, 256, 0, stream>>>(c2f, c2h, c2l, Bg*512);
  gemm(c2h, c2l, 512, 0, Wr3th, Wr3tl, 512, 0, c3, nullptr, nullptr, 256, 0,
       br3, 0, Bg, 256, 512, 1, 1, 0, 1, 1);

  // ---- final MLP ----
  catnorm_k<<<Bg, 256, 0, stream>>>(vall, c3, xcnh, xcnl, Bg);
  gemm(xcnh, xcnl, 512, 0, Wf1th, Wf1tl, 512, 0, nullptr, t1h, t1l, 1024, 0,
       bf1, 0, Bg, 1024, 512, 1, 1, 1, 1, 1);
  gemm(t1h, t1l, 1024, 0, Wf2th, Wf2tl, 1024, 0, nullptr, t2h, t2l, 512, 0,
       bf2, 0, Bg, 512, 1024, 1, 1, 1, 1, 1);
  gemm(t2h, t2l, 512, 0, Wf3th, Wf3tl, 512, 0, nullptr, t3h, t3l, 128, 0,
       bf3, 0, Bg, 128, 512, 1, 1, 1, 1, 1);
  gemm(t3h, t3l, 128, 0, Woth, Wotl, 128, 0, out, nullptr, nullptr, 2, 0,
       bo, 0, Bg, 2, 128, 1, 0, 0, 1, 1);
}

// Round 15
// 563.525 us; speedup vs baseline: 1.1344x; 1.0529x over previous
//
#include <hip/hip_runtime.h>
#include <math.h>

typedef unsigned short ushort_t;
typedef __attribute__((ext_vector_type(8))) short short8;
typedef __attribute__((ext_vector_type(8))) unsigned short ushort8v;
typedef __attribute__((ext_vector_type(4))) float float4v;
typedef __attribute__((ext_vector_type(4))) unsigned short ushort4v;

#define MPAD 30016
#define H1STR 136

// ---------------- utility ----------------
__device__ __forceinline__ float lrelu02(float v){ return v > 0.f ? v : 0.2f*v; }
__device__ __forceinline__ float elu_fast(float v){ return v > 0.f ? v : (__expf(v) - 1.f); }

__device__ __forceinline__ ushort_t f2bf(float x){
  unsigned u = __float_as_uint(x);
  return (ushort_t)((u + 0x7fffu + ((u >> 16) & 1u)) >> 16);
}
__device__ __forceinline__ float bf2f(ushort_t h){ return __uint_as_float(((unsigned)h) << 16); }

// monotone float<->unsigned for atomicMax pooling
__device__ __forceinline__ unsigned encf(float f){
  unsigned u = __float_as_uint(f);
  return (u & 0x80000000u) ? ~u : (u | 0x80000000u);
}
__device__ __forceinline__ float decf(unsigned u){
  return __uint_as_float((u >> 31) ? (u & 0x7FFFFFFFu) : ~u);
}

__device__ __forceinline__ void gll16(const void* g, void* l){
  __builtin_amdgcn_global_load_lds((const __attribute__((address_space(1))) void*)g,
                                   (__attribute__((address_space(3))) void*)l, 16, 0, 0);
}

// ---------------- batched CSR build (both branches) ----------------
__global__ void hist2_k(const int* __restrict__ ei1, const int* __restrict__ ei2,
                        int E, int N, int* deg){
  int idx = blockIdx.x*blockDim.x + threadIdx.x;
  if (idx < 2*E){
    int br = idx / E, e = idx - br*E;
    const int* ei = br ? ei2 : ei1;
    atomicAdd(&deg[br*N + ei[E + e]], 1);
  }
}

__global__ __launch_bounds__(1024)
void scanA_k(const int* __restrict__ deg, int* __restrict__ rowptr, int* __restrict__ bsum, int n){
  int br = blockIdx.y;
  int t = threadIdx.x;
  int i = blockIdx.x*1024 + t;
  __shared__ int s[1024];
  int v = (i < n) ? (deg[br*n + i] + 1) : 0;   // +1 = self-loop
  s[t] = v; __syncthreads();
  for (int off = 1; off < 1024; off <<= 1){
    int x = (t >= off) ? s[t - off] : 0;
    __syncthreads();
    s[t] += x;
    __syncthreads();
  }
  if (i < n) rowptr[br*(n+1) + i] = s[t] - v;
  if (t == 1023) bsum[br*gridDim.x + blockIdx.x] = s[1023];
}

__global__ void scanB_k(int* bsum, int nb){
  int br = threadIdx.x;
  if (br < 2){
    int run = 0;
    for (int i = 0; i < nb; ++i){ int v = bsum[br*nb + i]; bsum[br*nb + i] = run; run += v; }
  }
}

__global__ __launch_bounds__(1024)
void scanC_k(const int* __restrict__ bsum, int* __restrict__ rowptr, int* __restrict__ cursor,
             int n, int nb, int total){
  int br = blockIdx.y;
  int i = blockIdx.x*1024 + threadIdx.x;
  int add = bsum[br*nb + blockIdx.x];
  if (i < n){
    int nv = rowptr[br*(n+1) + i] + add;
    rowptr[br*(n+1) + i] = nv;
    cursor[br*n + i] = nv;
  }
  if (i == 0) rowptr[br*(n+1) + n] = total;
}

// edges + self-loops in one pass (order within a row irrelevant)
__global__ void fill_csr2_k(const int* __restrict__ ei1, const int* __restrict__ ei2,
                            int E, int N, int* cursor, int* csr){
  int idx = blockIdx.x*blockDim.x + threadIdx.x;
  if (idx < 2*E){
    int br = idx / E, e = idx - br*E;
    const int* ei = br ? ei2 : ei1;
    int dst = ei[E + e];
    int pos = atomicAdd(&cursor[br*N + dst], 1);
    csr[br*(E+N) + pos] = ei[e];
  } else if (idx < 2*E + 2*N){
    int r = idx - 2*E;
    int br = r / N, i = r - br*N;
    int pos = atomicAdd(&cursor[br*N + i], 1);
    csr[br*(E+N) + pos] = i;
  }
}

// ---------------- attention score precompute (merged) ----------------
__global__ void mkattn_k(const float* __restrict__ W1, const float* __restrict__ a_src1,
                         const float* __restrict__ a_dst1,
                         const float* __restrict__ W2, const float* __restrict__ a_src2,
                         const float* __restrict__ a_dst2,
                         float* As, float* Ad, float* vs, float* vd){
  int idx = blockIdx.x*blockDim.x + threadIdx.x;
  if (idx < 780){
    int f = idx / 10, h = idx % 10;
    float ss = 0.f, sd = 0.f;
    for (int c = 0; c < 128; ++c){
      float w = W1[f*1280 + h*128 + c];
      ss += w * a_src1[h*128 + c];
      sd += w * a_dst1[h*128 + c];
    }
    As[idx] = ss; Ad[idx] = sd;
  } else if (idx < 2060){
    int k = idx - 780;
    float ss = 0.f, sd = 0.f;
    for (int c = 0; c < 128; ++c){
      float w = W2[k*128 + c];
      ss += w * a_src2[c]; sd += w * a_dst2[c];
    }
    vs[k] = ss; vd[k] = sd;
  }
}

// node-per-thread alpha1 (both branches); As/Ad staged in LDS
__global__ __launch_bounds__(256)
void alpha1b_k(const float* __restrict__ x1, const float* __restrict__ x2,
               const float* __restrict__ As, const float* __restrict__ Ad,
               float* as1, float* ad1, int n){
  __shared__ float sAs[780], sAd[780];
  int t = threadIdx.x;
  for (int k = t; k < 780; k += 256){ sAs[k] = As[k]; sAd[k] = Ad[k]; }
  __syncthreads();
  int idx = blockIdx.x*256 + t;
  if (idx >= 2*n) return;
  int br = idx / n, i = idx - br*n;
  const float* xr = (br ? x2 : x1) + (size_t)i*78;
  float ss[10], sd[10];
  #pragma unroll
  for (int h = 0; h < 10; ++h){ ss[h] = 0.f; sd[h] = 0.f; }
  for (int f = 0; f < 78; ++f){
    float xv = xr[f];
    #pragma unroll
    for (int h = 0; h < 10; ++h){
      ss[h] += xv * sAs[f*10 + h];
      sd[h] += xv * sAd[f*10 + h];
    }
  }
  #pragma unroll
  for (int h = 0; h < 10; ++h){
    as1[(size_t)idx*10 + h] = ss[h];
    ad1[(size_t)idx*10 + h] = sd[h];
  }
}

// ---------------- GATConv1 one-pass softmax + aggregate (both branches) ----------------
__global__ __launch_bounds__(64)
void gat1_agg_k(const int* __restrict__ rowptr2, const int* __restrict__ csr2,
                const float* __restrict__ x1, const float* __restrict__ x2,
                const float* __restrict__ as1b, const float* __restrict__ ad1b,
                ushort_t* __restrict__ yh, int n, int E){
  int gi = blockIdx.x;
  int br = (gi >= n) ? 1 : 0;
  int i = gi - br*n;
  int t = threadIdx.x;
  const int* rowptr = rowptr2 + (size_t)br*(n+1);
  const int* csr    = csr2 + (size_t)br*(E+n);
  const float* x    = br ? x2 : x1;
  const float* as1  = as1b + (size_t)br*n*10;
  ushort_t* yb      = yh + (size_t)br*10*MPAD*96;

  __shared__ float adi[10], rden[10], wE[10], xs[78];
  int beg = rowptr[i], end = rowptr[i+1];
  if (t < 10) adi[t] = ad1b[(size_t)gi*10 + t];
  __syncthreads();
  float den = 0.f;
  float acc[13];
  int hh[13], cc[13];
  #pragma unroll
  for (int k = 0; k < 13; ++k){
    acc[k] = 0.f;
    int j = t + 64*k;
    hh[k] = (j < 780) ? (j/78) : 0;
    cc[k] = (j < 780) ? (j%78) : 0;
  }
  for (int e = beg; e < end; ++e){
    int s = csr[e];
    if (t < 10){
      float w = __expf(lrelu02(as1[(size_t)s*10 + t] + adi[t]));
      wE[t] = w; den += w;
    }
    for (int c = t; c < 78; c += 64) xs[c] = x[(size_t)s*78 + c];
    __syncthreads();
    #pragma unroll
    for (int k = 0; k < 13; ++k){
      int j = t + 64*k;
      if (j < 780) acc[k] += wE[hh[k]] * xs[cc[k]];
    }
    __syncthreads();
  }
  if (t < 10) rden[t] = 1.f/(den + 1e-16f);
  __syncthreads();
  #pragma unroll
  for (int k = 0; k < 13; ++k){
    int j = t + 64*k;
    if (j < 780) yb[((size_t)hh[k]*MPAD + i)*96 + cc[k]] = f2bf(acc[k]*rden[hh[k]]);
  }
  for (int p = t; p < 180; p += 64){
    int h = p/18, c = 78 + p%18;
    yb[((size_t)h*MPAD + i)*96 + c] = 0;
  }
}

// ---------------- fused branch conv (both branches; bf16-hi weights; bf16 h2 out) ----------------
__global__ __launch_bounds__(256)
void branch_conv_k(const ushort_t* __restrict__ yall,
                   const ushort_t* __restrict__ W1h, const ushort_t* __restrict__ W2h,
                   const float* __restrict__ b1, const float* __restrict__ vs,
                   const float* __restrict__ vd,
                   ushort_t* __restrict__ h2all, float* __restrict__ as2all,
                   float* __restrict__ ad2all, int M){
  const int NBLK = MPAD/64;
  int br = blockIdx.x / NBLK;
  int bi = blockIdx.x - br*NBLK;
  const ushort_t* y = yall + (size_t)br*10*MPAD*96;
  ushort_t* h2 = h2all + (size_t)br*MPAD*128;
  float* as2 = as2all + (size_t)br*MPAD;
  float* ad2 = ad2all + (size_t)br*MPAD;

  __shared__ ushort_t stage[2][6144];   // [A 2048][Bh 4096]
  __shared__ ushort_t h1t[64*H1STR];
  __shared__ float red[256];

  int tid = threadIdx.x, lane = tid & 63, wave = tid >> 6;
  int row0 = bi*64;
  int wm = (wave & 1)*32, wn = (wave >> 1)*64;
  int lr = lane & 15, quad = lane >> 4;
  int sr = lane >> 2;
  int skc = (((lane & 3) ^ ((lane >> 3) & 3)) * 8);
  int qs  = (quad ^ ((lr >> 1) & 3)) * 8;

  float4v acc2[2][4];
  #pragma unroll
  for (int i = 0; i < 2; ++i)
    #pragma unroll
    for (int j = 0; j < 4; ++j)
      acc2[i][j] = (float4v){0.f, 0.f, 0.f, 0.f};
  float rps[8], rpd[8];
  #pragma unroll
  for (int z = 0; z < 8; ++z){ rps[z] = 0.f; rpd[z] = 0.f; }

  for (int h = 0; h < 10; ++h){
    const ushort_t* gA   = y   + ((size_t)h*MPAD + row0 + wave*16 + sr)*96 + skc;
    const ushort_t* gB0h = W1h + ((size_t)(h*128 + wave*32      + sr))*96 + skc;
    const ushort_t* gB1h = W1h + ((size_t)(h*128 + wave*32 + 16 + sr))*96 + skc;
    const ushort_t* gC0h = W2h + ((size_t)(wave*32      + sr))*1280 + h*128 + skc;
    const ushort_t* gC1h = W2h + ((size_t)(wave*32 + 16 + sr))*1280 + h*128 + skc;

    auto issue1 = [&](int p, int kt){
      ushort_t* st = &stage[p][0];
      gll16(gA   + kt, st + wave*512);
      gll16(gB0h + kt, st + 2048 + wave*1024);
      gll16(gB1h + kt, st + 2048 + wave*1024 + 512);
    };
    auto issue2 = [&](int p, int kt){
      ushort_t* st = &stage[p][0];
      gll16(gC0h + kt, st + 2048 + wave*1024);
      gll16(gC1h + kt, st + 2048 + wave*1024 + 512);
    };

    // ---- P1: h1e_h = y_h @ W1_h (K=96) ----
    __syncthreads();
    issue1(0, 0);
    float4v acc1[2][4];
    #pragma unroll
    for (int i = 0; i < 2; ++i)
      #pragma unroll
      for (int j = 0; j < 4; ++j)
        acc1[i][j] = (float4v){0.f, 0.f, 0.f, 0.f};
    int p = 0;
    #pragma unroll
    for (int it = 0; it < 3; ++it){
      __syncthreads();
      if (it < 2) issue1(p ^ 1, (it + 1)*32);
      const ushort_t* sm = &stage[p][0];
      short8 af[2], bhf[4];
      #pragma unroll
      for (int t2 = 0; t2 < 2; ++t2)
        af[t2] = *(const short8*)&sm[(wm + t2*16 + lr)*32 + qs];
      #pragma unroll
      for (int j = 0; j < 4; ++j)
        bhf[j] = *(const short8*)&sm[2048 + (wn + j*16 + lr)*32 + qs];
      #pragma unroll
      for (int i = 0; i < 2; ++i)
        #pragma unroll
        for (int j = 0; j < 4; ++j)
          acc1[i][j] = __builtin_amdgcn_mfma_f32_16x16x32_bf16(af[i], bhf[j], acc1[i][j], 0, 0, 0);
      p ^= 1;
    }

    // ---- ELU + bias; write h1t; accumulate alpha2 from fp32 values ----
    #pragma unroll
    for (int j = 0; j < 4; ++j){
      int col = wn + j*16 + lr;
      float bv  = b1[h*128 + col];
      float vsv = vs[h*128 + col];
      float vdv = vd[h*128 + col];
      #pragma unroll
      for (int i = 0; i < 2; ++i){
        #pragma unroll
        for (int r = 0; r < 4; ++r){
          float v = elu_fast(acc1[i][j][r] + bv);
          h1t[(wm + i*16 + quad*4 + r)*H1STR + col] = f2bf(v);
          rps[i*4 + r] += v * vsv;
          rpd[i*4 + r] += v * vdv;
        }
      }
    }
    __syncthreads();

    // ---- P2: h2 += h1e_tile @ W2[h*128:(h+1)*128, :] (K=128) ----
    issue2(0, 0);
    p = 0;
    #pragma unroll
    for (int it = 0; it < 4; ++it){
      __syncthreads();
      if (it < 3) issue2(p ^ 1, (it + 1)*32);
      const ushort_t* sm = &stage[p][0];
      int kt = it*32;
      short8 af[2], bhf[4];
      #pragma unroll
      for (int t2 = 0; t2 < 2; ++t2)
        af[t2] = *(const short8*)&h1t[(wm + t2*16 + lr)*H1STR + kt + quad*8];
      #pragma unroll
      for (int j = 0; j < 4; ++j)
        bhf[j] = *(const short8*)&sm[2048 + (wn + j*16 + lr)*32 + qs];
      #pragma unroll
      for (int i = 0; i < 2; ++i)
        #pragma unroll
        for (int j = 0; j < 4; ++j)
          acc2[i][j] = __builtin_amdgcn_mfma_f32_16x16x32_bf16(af[i], bhf[j], acc2[i][j], 0, 0, 0);
      p ^= 1;
    }
  }

  // ---- h2 store (bf16) ----
  #pragma unroll
  for (int j = 0; j < 4; ++j){
    int col = wn + j*16 + lr;
    #pragma unroll
    for (int i = 0; i < 2; ++i){
      #pragma unroll
      for (int r = 0; r < 4; ++r){
        int row = row0 + wm + i*16 + quad*4 + r;
        if (row < M) h2[(size_t)row*128 + col] = f2bf(acc2[i][j][r]);
      }
    }
  }
  // ---- alpha2 reduce ----
  __syncthreads();
  #pragma unroll
  for (int z = 0; z < 8; ++z){
    float a = rps[z], d = rpd[z];
    #pragma unroll
    for (int mk = 1; mk <= 8; mk <<= 1){
      a += __shfl_xor(a, mk);
      d += __shfl_xor(d, mk);
    }
    if (lr == 0){
      int i = z >> 2, r = z & 3;
      int row = wm + i*16 + quad*4 + r;
      red[row*2 + (wave >> 1)] = a;
      red[128 + row*2 + (wave >> 1)] = d;
    }
  }
  __syncthreads();
  if (tid < 64){
    int grow = row0 + tid;
    if (grow < M){
      as2[grow] = red[tid*2] + red[tid*2 + 1];
      ad2[grow] = red[128 + tid*2] + red[128 + tid*2 + 1];
    }
  }
}

// ---------------- GATConv2 one-pass softmax + aggregate + atomic pool (bf16 h2) ----------------
__global__ __launch_bounds__(64)
void gat2_agg_k(const int* __restrict__ rowptr2, const int* __restrict__ csr2,
                const ushort_t* __restrict__ h2all, const float* __restrict__ as2all,
                const float* __restrict__ ad2all, const float* __restrict__ b2,
                const int* __restrict__ batch1, const int* __restrict__ batch2,
                unsigned* __restrict__ poolKey, int n, int E, int Bg){
  int gi = blockIdx.x;
  int br = (gi >= n) ? 1 : 0;
  int i = gi - br*n;
  int t = threadIdx.x;
  const int* rowptr = rowptr2 + (size_t)br*(n+1);
  const int* csr    = csr2 + (size_t)br*(E+n);
  const ushort_t* h2 = h2all + (size_t)br*MPAD*128;
  const float* as2  = as2all + (size_t)br*MPAD;
  float adi = ad2all[(size_t)br*MPAD + i];
  int beg = rowptr[i], end = rowptr[i+1];
  float den = 0.f, a0 = 0.f, a1 = 0.f;
  for (int e = beg; e < end; ++e){
    int s = csr[e];
    float w = __expf(lrelu02(as2[s] + adi));
    den += w;
    unsigned u = *(const unsigned*)&h2[(size_t)s*128 + 2*t];
    a0 += w * bf2f((ushort_t)(u & 0xffffu));
    a1 += w * bf2f((ushort_t)(u >> 16));
  }
  float r = 1.f/(den + 1e-16f);
  float o0 = elu_fast(a0*r + b2[2*t]);
  float o1 = elu_fast(a1*r + b2[2*t + 1]);
  int g = (br ? batch2 : batch1)[i];
  unsigned* pk = poolKey + ((size_t)br*Bg + g)*128;
  atomicMax(&pk[2*t], encf(o0));
  atomicMax(&pk[2*t + 1], encf(o1));
}

// ---------------- pool decode → split bf16 ----------------
__global__ void pool_decode_k(const unsigned* __restrict__ key,
                              ushort_t* __restrict__ ph, ushort_t* __restrict__ pl, int n){
  int i = blockIdx.x*blockDim.x + threadIdx.x;
  if (i < n){
    float v = decf(key[i]);
    ushort_t h = f2bf(v);
    ph[i] = h; pl[i] = f2bf(v - bf2f(h));
  }
}

// ---------------- row-wise L2 normalize → split bf16 (K-padded) ----------------
__global__ __launch_bounds__(256)
void l2norm_split_k(const float* __restrict__ in, int cols, int Kp,
                    ushort_t* __restrict__ oh, ushort_t* __restrict__ ol){
  int r = blockIdx.x, t = threadIdx.x;
  __shared__ float s[256];
  __shared__ float scaleS;
  const float* rp = in + (size_t)r*cols;
  float p = 0.f;
  for (int k = t; k < cols; k += 256){ float v = rp[k]; p += v*v; }
  s[t] = p; __syncthreads();
  for (int o = 128; o > 0; o >>= 1){
    if (t < o) s[t] += s[t+o];
    __syncthreads();
  }
  if (t == 0) scaleS = 1.f / fmaxf(sqrtf(s[0]), 1e-12f);
  __syncthreads();
  float sc = scaleS;
  for (int k = t; k < Kp; k += 256){
    float v = (k < cols) ? rp[k]*sc : 0.f;
    ushort_t h = f2bf(v);
    size_t o2 = (size_t)r*Kp + k;
    oh[o2] = h; ol[o2] = f2bf(v - bf2f(h));
  }
}

// ---------------- fused concat + l2norm + split ----------------
__global__ __launch_bounds__(256)
void catnorm_k(const float* __restrict__ vall, const float* __restrict__ c3,
               ushort_t* __restrict__ oh, ushort_t* __restrict__ ol, int Bg){
  int r = blockIdx.x, t = threadIdx.x;
  __shared__ float s[256];
  __shared__ float scaleS;
  auto val = [&](int c)->float{
    if (c < 128) return vall[(size_t)r*128 + c];
    if (c < 256) return vall[((size_t)Bg + r)*128 + (c - 128)];
    return c3[(size_t)r*256 + (c - 256)];
  };
  float v0 = val(t), v1 = val(t + 256);
  s[t] = v0*v0 + v1*v1; __syncthreads();
  for (int o = 128; o > 0; o >>= 1){
    if (t < o) s[t] += s[t+o];
    __syncthreads();
  }
  if (t == 0) scaleS = 1.f / fmaxf(sqrtf(s[0]), 1e-12f);
  __syncthreads();
  float sc = scaleS;
  float a = v0*sc, b = v1*sc;
  ushort_t ha = f2bf(a), hb = f2bf(b);
  size_t o2 = (size_t)r*512;
  oh[o2 + t] = ha;       ol[o2 + t] = f2bf(a - bf2f(ha));
  oh[o2 + 256 + t] = hb; ol[o2 + 256 + t] = f2bf(b - bf2f(hb));
}

// relu + split (post split-K reduction)
__global__ void act_split_k(const float* __restrict__ in, ushort_t* __restrict__ oh,
                            ushort_t* __restrict__ ol, int n){
  int i = blockIdx.x*blockDim.x + threadIdx.x;
  if (i < n){
    float v = fmaxf(in[i], 0.f);
    ushort_t h = f2bf(v);
    oh[i] = h; ol[i] = f2bf(v - bf2f(h));
  }
}

// ---------------- merged weight transpose + split ----------------
__device__ __forceinline__ void split_one(const float* __restrict__ W, int ldw, int colStride,
                                          int N, int K, int Np, int Kp,
                                          ushort_t* __restrict__ dh, ushort_t* __restrict__ dl,
                                          int idx){
  int n  = idx % Np;
  int r  = idx / Np;
  int k4 = r % (Kp >> 2);
  int b  = r / (Kp >> 2);
  size_t o = ((size_t)b*Np + n)*Kp + (size_t)k4*4;
  ushort4v hv, lv;
  #pragma unroll
  for (int kk = 0; kk < 4; ++kk){
    int k = k4*4 + kk;
    float v = (n < N && k < K) ? W[(size_t)k*ldw + (size_t)b*colStride + n] : 0.f;
    ushort_t h = f2bf(v);
    hv[kk] = h; lv[kk] = f2bf(v - bf2f(h));
  }
  *(ushort4v*)&dh[o] = hv;
  if (dl) *(ushort4v*)&dl[o] = lv;
}

struct SplitTable {
  const float *W1, *W2, *Wg, *Wr1, *Wr2, *Wr3, *Wf1, *Wf2, *Wf3, *Wo;
  ushort_t *W1h,*W2h,*Wgh,*Wgl,*Wr1h,*Wr1l,*Wr2h,*Wr2l;
  ushort_t *Wr3h,*Wr3l,*Wf1h,*Wf1l,*Wf2h,*Wf2l,*Wf3h,*Wf3l,*Woh,*Wol;
};

__global__ void split_all_k(SplitTable T){
  int idx = blockIdx.x*blockDim.x + threadIdx.x;
  if      (idx <   30720) split_one(T.W1, 1280, 128, 128,   78,  128,   96, T.W1h, nullptr, idx);
  else if (idx <   71680) split_one(T.W2,  128,   0, 128, 1280,  128, 1280, T.W2h, nullptr, idx -   30720);
  else if (idx <   75776) split_one(T.Wg,  128,   0, 128,  128,  128,  128, T.Wgh, T.Wgl, idx -   71680);
  else if (idx <  567296) split_one(T.Wr1,2048,   0,2048,  954, 2048,  960, T.Wr1h,T.Wr1l,idx -   75776);
  else if (idx <  829440) split_one(T.Wr2, 512,   0, 512, 2048,  512, 2048, T.Wr2h,T.Wr2l,idx -  567296);
  else if (idx <  862208) split_one(T.Wr3, 256,   0, 256,  512,  256,  512, T.Wr3h,T.Wr3l,idx -  829440);
  else if (idx <  993280) split_one(T.Wf1,1024,   0,1024,  512, 1024,  512, T.Wf1h,T.Wf1l,idx -  862208);
  else if (idx < 1124352) split_one(T.Wf2, 512,   0, 512, 1024,  512, 1024, T.Wf2h,T.Wf2l,idx -  993280);
  else if (idx < 1140736) split_one(T.Wf3, 128,   0, 128,  512,  128,  512, T.Wf3h,T.Wf3l,idx - 1124352);
  else if (idx < 1142784) split_one(T.Wo,    2,   0,   2,  128,   64,  128, T.Woh, T.Wol, idx - 1140736);
}

// ---------------- split-bf16 MFMA GEMM (MLP path) ----------------
__global__ __launch_bounds__(256)
void gemm_split(const ushort_t* __restrict__ Ahp, const ushort_t* __restrict__ Alp, int lda, long long sA,
                const ushort_t* __restrict__ Bhp, const ushort_t* __restrict__ Blp, int ldb, long long sB,
                float* __restrict__ C, ushort_t* __restrict__ Ch, ushort_t* __restrict__ Cl,
                int ldc, long long sC,
                const float* __restrict__ bias, int sBias,
                int M, int Nc, int K, int act, int outMode, int kSplit, int aSplit){
  int zb = blockIdx.z;
  int b = zb / kSplit, kc = zb - b*kSplit;
  Ahp += (long long)b*sA;
  Bhp += (long long)b*sB; Blp += (long long)b*sB;
  long long cOff = (long long)b*sC;
  int Kc = K / kSplit;
  int kb = kc*Kc;
  int nIter = Kc / 32;

  __shared__ ushort_t smem[18048];

  int tid = threadIdx.x, lane = tid & 63, wave = tid >> 6;
  int row0 = blockIdx.y*64, col0 = blockIdx.x*64;
  int wm = (wave & 1)*32, wn = (wave >> 1)*32;
  int lr = lane & 15, quad = lane >> 4;
  int qs = (quad ^ ((lr >> 1) & 3)) * 8;

  int srow = wave*16 + (lane >> 2);
  int skc  = (((lane & 3) ^ ((lane >> 3) & 3)) * 8);
  const ushort_t* gAh = Ahp + (long long)(row0 + srow)*lda + skc + kb;
  const ushort_t* gAl = aSplit ? (Alp + (long long)b*sA + (long long)(row0 + srow)*lda + skc + kb) : gAh;
  const ushort_t* gBh = Bhp + (long long)(col0 + srow)*ldb + skc + kb;
  const ushort_t* gBl = Blp + (long long)(col0 + srow)*ldb + skc + kb;

  float4v acc[2][2];
  #pragma unroll
  for (int i = 0; i < 2; ++i)
    #pragma unroll
    for (int j = 0; j < 2; ++j)
      acc[i][j] = (float4v){0.f, 0.f, 0.f, 0.f};

  auto issue = [&](int p, int kt){
    ushort_t* base = &smem[p*8192 + wave*512];
    gll16(gAh + kt, base);
    if (aSplit) gll16(gAl + kt, base + 2048);
    gll16(gBh + kt, base + 4096);
    gll16(gBl + kt, base + 6144);
  };

  issue(0, 0);
  int p = 0;
  for (int it = 0; it < nIter; ++it){
    __syncthreads();
    if (it + 1 < nIter) issue(p ^ 1, (it + 1)*32);
    const ushort_t* sm = &smem[p*8192];
    short8 ah[2], al[2], bh[2], bl[2];
    #pragma unroll
    for (int t2 = 0; t2 < 2; ++t2){
      int ao = (wm + t2*16 + lr)*32 + qs;
      int bo = (wn + t2*16 + lr)*32 + qs;
      ah[t2] = *(const short8*)&sm[ao];
      if (aSplit) al[t2] = *(const short8*)&sm[2048 + ao];
      bh[t2] = *(const short8*)&sm[4096 + bo];
      bl[t2] = *(const short8*)&sm[6144 + bo];
    }
    #pragma unroll
    for (int i = 0; i < 2; ++i)
      #pragma unroll
      for (int j = 0; j < 2; ++j){
        if (aSplit)
          acc[i][j] = __builtin_amdgcn_mfma_f32_16x16x32_bf16(al[i], bh[j], acc[i][j], 0, 0, 0);
        acc[i][j] = __builtin_amdgcn_mfma_f32_16x16x32_bf16(ah[i], bl[j], acc[i][j], 0, 0, 0);
        acc[i][j] = __builtin_amdgcn_mfma_f32_16x16x32_bf16(ah[i], bh[j], acc[i][j], 0, 0, 0);
      }
    p ^= 1;
  }
  __syncthreads();

  if (outMode == 0 || outMode == 2){
    #pragma unroll
    for (int j = 0; j < 2; ++j){
      int col = col0 + wn + j*16 + lr;
      if (col >= Nc) continue;
      float bv = (bias && kc == 0) ? bias[(long long)b*sBias + col] : 0.f;
      #pragma unroll
      for (int i = 0; i < 2; ++i){
        #pragma unroll
        for (int r = 0; r < 4; ++r){
          int row = row0 + wm + i*16 + quad*4 + r;
          if (row >= M) continue;
          float v = acc[i][j][r] + bv;
          if (act == 1) v = fmaxf(v, 0.f);
          else if (act == 2) v = elu_fast(v);
          long long o = cOff + (long long)row*ldc + col;
          if (outMode == 0) C[o] = v;
          else atomicAdd(&C[o], v);
        }
      }
    }
  } else {
    float* ftile = (float*)smem;
    #pragma unroll
    for (int i = 0; i < 2; ++i)
      #pragma unroll
      for (int j = 0; j < 2; ++j)
        #pragma unroll
        for (int r = 0; r < 4; ++r)
          ftile[(wm + i*16 + quad*4 + r)*68 + wn + j*16 + lr] = acc[i][j][r];
    __syncthreads();
    int row = tid >> 2, ch = (tid & 3)*16;
    int grow = row0 + row;
    if (grow < M){
      if (col0 + 64 <= Nc){
        long long o = cOff + (long long)grow*ldc + col0 + ch;
        #pragma unroll
        for (int g = 0; g < 2; ++g){
          ushort8v hv, lv;
          #pragma unroll
          for (int c = 0; c < 8; ++c){
            int cc2 = ch + g*8 + c;
            float v = ftile[row*68 + cc2];
            if (bias) v += bias[(long long)b*sBias + col0 + cc2];
            if (act == 1) v = fmaxf(v, 0.f);
            else if (act == 2) v = elu_fast(v);
            hv[c] = f2bf(v);
            lv[c] = f2bf(v - bf2f(hv[c]));
          }
          *(ushort8v*)&Ch[o + g*8] = hv;
          *(ushort8v*)&Cl[o + g*8] = lv;
        }
      } else {
        for (int c = 0; c < 16; ++c){
          int col = col0 + ch + c;
          if (col >= Nc) break;
          float v = ftile[row*68 + ch + c];
          if (bias) v += bias[(long long)b*sBias + col];
          if (act == 1) v = fmaxf(v, 0.f);
          else if (act == 2) v = elu_fast(v);
          long long o = cOff + (long long)grow*ldc + col;
          ushort_t h = f2bf(v);
          Ch[o] = h;
          Cl[o] = f2bf(v - bf2f(h));
        }
      }
    }
  }
}

// ---------------- host launch ----------------
extern "C" void kernel_launch(void* const* d_in, const int* in_sizes, int n_in,
                              void* d_out, int out_size, void* d_ws, size_t ws_size,
                              hipStream_t stream){
  const float* x1     = (const float*)d_in[0];
  const int*   ei1    = (const int*)  d_in[1];
  const int*   batch1 = (const int*)  d_in[2];
  const float* x2     = (const float*)d_in[3];
  const int*   ei2    = (const int*)  d_in[4];
  const int*   batch2 = (const int*)  d_in[5];
  const float* cell   = (const float*)d_in[6];
  const float* W1     = (const float*)d_in[7];
  const float* a_src1 = (const float*)d_in[8];
  const float* a_dst1 = (const float*)d_in[9];
  const float* b1     = (const float*)d_in[10];
  const float* W2     = (const float*)d_in[11];
  const float* a_src2 = (const float*)d_in[12];
  const float* a_dst2 = (const float*)d_in[13];
  const float* b2     = (const float*)d_in[14];
  const float* Wg     = (const float*)d_in[15];
  const float* bg     = (const float*)d_in[16];
  const float* Wr1    = (const float*)d_in[17];
  const float* br1    = (const float*)d_in[18];
  const float* Wr2    = (const float*)d_in[19];
  const float* br2    = (const float*)d_in[20];
  const float* Wr3    = (const float*)d_in[21];
  const float* br3    = (const float*)d_in[22];
  const float* Wf1    = (const float*)d_in[23];
  const float* bf1    = (const float*)d_in[24];
  const float* Wf2    = (const float*)d_in[25];
  const float* bf2    = (const float*)d_in[26];
  const float* Wf3    = (const float*)d_in[27];
  const float* bf3    = (const float*)d_in[28];
  const float* Wo     = (const float*)d_in[29];
  const float* bo     = (const float*)d_in[30];
  float* out = (float*)d_out;
  (void)n_in; (void)out_size; (void)ws_size;

  const int N  = in_sizes[0] / 78;
  const int E  = in_sizes[1] / 2;
  const int Bg = in_sizes[6] / 954;

  char* wsb = (char*)d_ws;
  size_t off = 0;
  auto alloc = [&](size_t bytes)->char*{
    char* p = wsb + off; off += ((bytes + 255)/256)*256; return p;
  };

  // Y region: yh (both branches) during branch phase; MLP bufs alias after
  char* Yb = alloc((size_t)2*10*MPAD*96*2);
  ushort_t* yh = (ushort_t*)Yb;
  size_t yoff = 0;
  auto yalloc = [&](size_t bytes)->char*{
    char* p = Yb + yoff; yoff += ((bytes + 255)/256)*256; return p;
  };
  ushort_t* cnh  = (ushort_t*)yalloc((size_t)Bg*960*2);
  ushort_t* cnl  = (ushort_t*)yalloc((size_t)Bg*960*2);
  ushort_t* c1h  = (ushort_t*)yalloc((size_t)Bg*2048*2);
  ushort_t* c1l  = (ushort_t*)yalloc((size_t)Bg*2048*2);
  ushort_t* c2h  = (ushort_t*)yalloc((size_t)Bg*512*2);
  ushort_t* c2l  = (ushort_t*)yalloc((size_t)Bg*512*2);
  float*    c3   = (float*)   yalloc((size_t)Bg*256*4);
  ushort_t* xcnh = (ushort_t*)yalloc((size_t)Bg*512*2);
  ushort_t* xcnl = (ushort_t*)yalloc((size_t)Bg*512*2);
  ushort_t* t1h  = (ushort_t*)yalloc((size_t)Bg*1024*2);
  ushort_t* t1l  = (ushort_t*)yalloc((size_t)Bg*1024*2);
  ushort_t* t2h  = (ushort_t*)yalloc((size_t)Bg*512*2);
  ushort_t* t2l  = (ushort_t*)yalloc((size_t)Bg*512*2);
  ushort_t* t3h  = (ushort_t*)yalloc((size_t)Bg*128*2);
  ushort_t* t3l  = (ushort_t*)yalloc((size_t)Bg*128*2);
  ushort_t* pooledh = (ushort_t*)yalloc((size_t)2*Bg*128*2);
  ushort_t* pooledl = (ushort_t*)yalloc((size_t)2*Bg*128*2);
  float*    vall    = (float*)   yalloc((size_t)2*Bg*128*4);

  // zero-init region (single memset): c2f, poolKey, deg2
  size_t zElems = (size_t)Bg*512 + (size_t)2*Bg*128 + (size_t)2*N;
  float* zbase = (float*)alloc(zElems*4);
  float* c2f = zbase;
  unsigned* poolKey = (unsigned*)(c2f + (size_t)Bg*512);
  int* deg2 = (int*)(poolKey + (size_t)2*Bg*128);

  ushort_t* h2 = (ushort_t*)alloc((size_t)2*MPAD*128*2);
  float* as2 = (float*)alloc((size_t)2*MPAD*4);
  float* ad2 = (float*)alloc((size_t)2*MPAD*4);

  // transposed weights: W1/W2 hi-only; MLP weights split
  ushort_t* W1th = (ushort_t*)alloc((size_t)10*128*96*2);
  ushort_t* W2th = (ushort_t*)alloc((size_t)128*1280*2);
  ushort_t* Wgth = (ushort_t*)alloc((size_t)128*128*2);
  ushort_t* Wgtl = (ushort_t*)alloc((size_t)128*128*2);
  ushort_t* Wr1th= (ushort_t*)alloc((size_t)2048*960*2);
  ushort_t* Wr1tl= (ushort_t*)alloc((size_t)2048*960*2);
  ushort_t* Wr2th= (ushort_t*)alloc((size_t)512*2048*2);
  ushort_t* Wr2tl= (ushort_t*)alloc((size_t)512*2048*2);
  ushort_t* Wr3th= (ushort_t*)alloc((size_t)256*512*2);
  ushort_t* Wr3tl= (ushort_t*)alloc((size_t)256*512*2);
  ushort_t* Wf1th= (ushort_t*)alloc((size_t)1024*512*2);
  ushort_t* Wf1tl= (ushort_t*)alloc((size_t)1024*512*2);
  ushort_t* Wf2th= (ushort_t*)alloc((size_t)512*1024*2);
  ushort_t* Wf2tl= (ushort_t*)alloc((size_t)512*1024*2);
  ushort_t* Wf3th= (ushort_t*)alloc((size_t)128*512*2);
  ushort_t* Wf3tl= (ushort_t*)alloc((size_t)128*512*2);
  ushort_t* Woth = (ushort_t*)alloc((size_t)64*128*2);
  ushort_t* Wotl = (ushort_t*)alloc((size_t)64*128*2);

  float* as1b = (float*)alloc((size_t)2*N*10*4);
  float* ad1b = (float*)alloc((size_t)2*N*10*4);
  float* AsB  = (float*)alloc(780*4);
  float* AdB  = (float*)alloc(780*4);
  float* vs   = (float*)alloc(1280*4);
  float* vd   = (float*)alloc(1280*4);
  int* rowptr2 = (int*)alloc((size_t)2*(N+1)*4);
  int* cursor2 = (int*)alloc((size_t)2*N*4);
  int* csr2    = (int*)alloc((size_t)2*(E+N)*4);
  int* bsum    = (int*)alloc((size_t)2*64*4);

  auto gemm = [&](const ushort_t* Ah_, const ushort_t* Al_, int lda, long long sA_,
                  const ushort_t* Bh_, const ushort_t* Bl_, int ldb, long long sB_,
                  float* C_, ushort_t* Ch_, ushort_t* Cl_, int ldc, long long sC_,
                  const float* bias_, int sBias_, int M_, int N_, int K_, int batch_,
                  int act_, int mode_, int kSplit_, int aSplit_){
    dim3 grid((N_ + 63)/64, (M_ + 63)/64, batch_*kSplit_);
    gemm_split<<<grid, 256, 0, stream>>>(Ah_, Al_, lda, sA_, Bh_, Bl_, ldb, sB_,
                                         C_, Ch_, Cl_, ldc, sC_, bias_, sBias_,
                                         M_, N_, K_, act_, mode_, kSplit_, aSplit_);
  };

  // ---- init + weight prep ----
  hipMemsetAsync(zbase, 0, zElems*4, stream);
  SplitTable T;
  T.W1 = W1; T.W2 = W2; T.Wg = Wg; T.Wr1 = Wr1; T.Wr2 = Wr2; T.Wr3 = Wr3;
  T.Wf1 = Wf1; T.Wf2 = Wf2; T.Wf3 = Wf3; T.Wo = Wo;
  T.W1h = W1th; T.W2h = W2th; T.Wgh = Wgth; T.Wgl = Wgtl;
  T.Wr1h = Wr1th; T.Wr1l = Wr1tl; T.Wr2h = Wr2th; T.Wr2l = Wr2tl;
  T.Wr3h = Wr3th; T.Wr3l = Wr3tl; T.Wf1h = Wf1th; T.Wf1l = Wf1tl;
  T.Wf2h = Wf2th; T.Wf2l = Wf2tl; T.Wf3h = Wf3th; T.Wf3l = Wf3tl;
  T.Woh = Woth; T.Wol = Wotl;
  split_all_k<<<(1142784 + 255)/256, 256, 0, stream>>>(T);
  mkattn_k<<<(2060 + 255)/256, 256, 0, stream>>>(W1, a_src1, a_dst1, W2, a_src2, a_dst2,
                                                 AsB, AdB, vs, vd);
  alpha1b_k<<<((2*N) + 255)/256, 256, 0, stream>>>(x1, x2, AsB, AdB, as1b, ad1b, N);

  // ---- batched CSR build ----
  const int NB = (N + 1023)/1024;
  hist2_k<<<((2*E) + 255)/256, 256, 0, stream>>>(ei1, ei2, E, N, deg2);
  scanA_k<<<dim3(NB, 2), 1024, 0, stream>>>(deg2, rowptr2, bsum, N);
  scanB_k<<<1, 64, 0, stream>>>(bsum, NB);
  scanC_k<<<dim3(NB, 2), 1024, 0, stream>>>(bsum, rowptr2, cursor2, N, NB, E + N);
  fill_csr2_k<<<((2*E + 2*N) + 255)/256, 256, 0, stream>>>(ei1, ei2, E, N, cursor2, csr2);

  // ---- branches (batched) ----
  gat1_agg_k<<<2*N, 64, 0, stream>>>(rowptr2, csr2, x1, x2, as1b, ad1b, yh, N, E);
  branch_conv_k<<<2*(MPAD/64), 256, 0, stream>>>(yh, W1th, W2th,
                                                 b1, vs, vd, h2, as2, ad2, N);
  gat2_agg_k<<<2*N, 64, 0, stream>>>(rowptr2, csr2, h2, as2, ad2, b2,
                                     batch1, batch2, poolKey, N, E, Bg);
  pool_decode_k<<<((2*Bg*128) + 255)/256, 256, 0, stream>>>(poolKey, pooledh, pooledl, 2*Bg*128);
  gemm(pooledh, pooledl, 128, 0, Wgth, Wgtl, 128, 0,
       vall, nullptr, nullptr, 128, 0, bg, 0, 2*Bg, 128, 128, 1, 1, 0, 1, 1);

  // ---- cell MLP ----
  l2norm_split_k<<<Bg, 256, 0, stream>>>(cell, 954, 960, cnh, cnl);
  gemm(cnh, cnl, 960, 0, Wr1th, Wr1tl, 960, 0, nullptr, c1h, c1l, 2048, 0,
       br1, 0, Bg, 2048, 960, 1, 1, 1, 1, 1);
  gemm(c1h, c1l, 2048, 0, Wr2th, Wr2tl, 2048, 0, c2f, nullptr, nullptr, 512, 0,
       br2, 0, Bg, 512, 2048, 1, 0, 2, 4, 1);
  act_split_k<<<((Bg*512) + 255)/256, 256, 0, stream>>>(c2f, c2h, c2l, Bg*512);
  gemm(c2h, c2l, 512, 0, Wr3th, Wr3tl, 512, 0, c3, nullptr, nullptr, 256, 0,
       br3, 0, Bg, 256, 512, 1, 1, 0, 1, 1);

  // ---- final MLP ----
  catnorm_k<<<Bg, 256, 0, stream>>>(vall, c3, xcnh, xcnl, Bg);
  gemm(xcnh, xcnl, 512, 0, Wf1th, Wf1tl, 512, 0, nullptr, t1h, t1l, 1024, 0,
       bf1, 0, Bg, 1024, 512, 1, 1, 1, 1, 1);
  gemm(t1h, t1l, 1024, 0, Wf2th, Wf2tl, 1024, 0, nullptr, t2h, t2l, 512, 0,
       bf2, 0, Bg, 512, 1024, 1, 1, 1, 1, 1);
  gemm(t2h, t2l, 512, 0, Wf3th, Wf3tl, 512, 0, nullptr, t3h, t3l, 128, 0,
       bf3, 0, Bg, 128, 512, 1, 1, 1, 1, 1);
  gemm(t3h, t3l, 128, 0, Woth, Wotl, 128, 0, out, nullptr, nullptr, 2, 0,
       bo, 0, Bg, 2, 128, 1, 0, 0, 1, 1);
}